// Round 5
// baseline (1167.125 us; speedup 1.0000x reference)
//
#include <hip/hip_runtime.h>
#include <math.h>

// ExpressionPerformer: B=16,G=2048,D=256,H=8,dh=32,FFN=1024,L=4
// Round-5:
//  - revert to BK=32 dbuf prefetch-after-barrier (R4's 64KB slab killed
//    occupancy, replicating m132). Hiding mechanism = TLP, so:
//  - 512-thread blocks, wave-tile 32x64 (acc 32 VGPR) -> ~2x resident waves
//  - LayerNorm fused into QKV / FFN-up GEMM A-staging (K=256 = full LN row):
//    stats pre-pass + normalize during staging; ln kernels and hn buffer gone.

#define GG 2048
#define DD 256
#define NROWS 32768
#define NC 32
#define CS 64

typedef __attribute__((ext_vector_type(8))) short bf16x8;
typedef __attribute__((ext_vector_type(4))) float f32x4;

__device__ __forceinline__ short f2bf(float f) {
  union { float f; unsigned u; } v; v.f = f;
  unsigned r = v.u + 0x7FFFu + ((v.u >> 16) & 1u);
  return (short)(r >> 16);
}
__device__ __forceinline__ float bf2f(short s) {
  union { unsigned u; float f; } v; v.u = ((unsigned)(unsigned short)s) << 16;
  return v.f;
}
__device__ __forceinline__ void gld16(const short* g, short* l) {
  __builtin_amdgcn_global_load_lds(
      (const __attribute__((address_space(1))) void*)g,
      (__attribute__((address_space(3))) void*)l, 16, 0, 0);
}
__device__ __forceinline__ float fast_gelu(float x) {
  float y = 1.595769122f * (x + 0.044715f * x * x * x);
  return x / (1.0f + __expf(-y));
}

// ---------------- embed ------------------------------------------------------
__global__ __launch_bounds__(256) void embed_kernel(
    const float* __restrict__ x, const float* __restrict__ ge,
    const float* __restrict__ invf, float* __restrict__ h) {
  int bg = blockIdx.x * 4 + (threadIdx.x >> 6);
  int g = bg & (GG - 1);
  int lane = threadIdx.x & 63;
  float xv = x[bg];
  int d = lane * 4;
  float4 e;
  if (lane < 32) {
    float4 f = *(const float4*)&invf[d];
    e.x = sinf(xv * f.x); e.y = sinf(xv * f.y);
    e.z = sinf(xv * f.z); e.w = sinf(xv * f.w);
  } else {
    float4 f = *(const float4*)&invf[d - 128];
    e.x = cosf(xv * f.x); e.y = cosf(xv * f.y);
    e.z = cosf(xv * f.z); e.w = cosf(xv * f.w);
  }
  if (xv == -10.0f) { e.x = 0.f; e.y = 0.f; e.z = 0.f; e.w = 0.f; }
  float4 gv = *(const float4*)&ge[(size_t)g * DD + d];
  float4 o; o.x = gv.x + e.x; o.y = gv.y + e.y; o.z = gv.z + e.z; o.w = gv.w + e.w;
  *(float4*)&h[(size_t)bg * DD + d] = o;
}

// ---------------- weight convert+transpose -----------------------------------
__global__ __launch_bounds__(256) void prep_weights(
    const float* __restrict__ Wq, const float* __restrict__ Wk,
    const float* __restrict__ Wv, const float* __restrict__ WU,
    const float* __restrict__ WV,
    short* __restrict__ TQ, short* __restrict__ TK, short* __restrict__ TV,
    short* __restrict__ TU, short* __restrict__ TVd) {
  int zz = blockIdx.z, l = blockIdx.y;
  const float* src; short* dst; int Kd, Nd;
  if (zz == 0) { src = Wq; dst = TQ; Kd = 256; Nd = 256; }
  else if (zz == 1) { src = Wk; dst = TK; Kd = 256; Nd = 256; }
  else if (zz == 2) { src = Wv; dst = TV; Kd = 256; Nd = 256; }
  else if (zz == 3) { src = WU; dst = TU; Kd = 256; Nd = 1024; }
  else { src = WV; dst = TVd; Kd = 1024; Nd = 256; }
  int tot = Kd * Nd;
  int e = blockIdx.x * 256 + threadIdx.x;
  if (e >= tot) return;
  int n = e / Kd, k = e - n * Kd;
  dst[(size_t)l * tot + e] = f2bf(src[(size_t)l * tot + (size_t)k * Nd + n]);
}

// ---------------- LN-fused GEMM: C = LN(h) @ BT^T + bias ----------------------
// M-tile 128, N-tile 128, K=256, BK=32, 8 waves (wave-tile 32x64), LDS dbuf.
// epi 0: z<2 -> square, bf16 out (QKV);  1: fast gelu, bf16 out (FFN-up)
__global__ __launch_bounds__(512) void lngemm(
    const float* __restrict__ h, const short* __restrict__ B0,
    const short* __restrict__ B1, const short* __restrict__ B2,
    const float* __restrict__ gamma, const float* __restrict__ beta,
    const float* __restrict__ bias0, const float* __restrict__ bias1,
    const float* __restrict__ bias2,
    short* __restrict__ o0, short* __restrict__ o1, short* __restrict__ o2,
    int N, int epi) {
  __shared__ __align__(16) short As[2][4096];
  __shared__ __align__(16) short Bs[2][4096];
  __shared__ __align__(16) float mrow[128];
  __shared__ __align__(16) float rrow[128];
  __shared__ __align__(16) float gls[256];
  __shared__ __align__(16) float bls[256];
  const int K = 256;
  int z = blockIdx.z;
  const short* Bt = (z == 0) ? B0 : (z == 1) ? B1 : B2;
  const float* bias = (z == 0) ? bias0 : (z == 1) ? bias1 : bias2;
  short* outz = (z == 0) ? o0 : (z == 1) ? o1 : o2;
  int m0 = blockIdx.x * 128, n0 = blockIdx.y * 128;
  int tid = threadIdx.x;
  int lane = tid & 63, w = tid >> 6;
  int q = lane >> 4, r = lane & 15;
  int wm = (w >> 1) * 32, wn = (w & 1) * 64;

  if (tid < 256) { gls[tid] = gamma[tid]; bls[tid] = beta[tid]; }
  // --- LN stats: 4 threads per row ---
  {
    int row = tid >> 2, seg = tid & 3;
    const float4* hp = (const float4*)(h + (size_t)(m0 + row) * DD + seg * 64);
    float s = 0.f, s2 = 0.f;
#pragma unroll
    for (int i = 0; i < 16; ++i) {
      float4 v = hp[i];
      s += v.x + v.y + v.z + v.w;
      s2 += v.x * v.x + v.y * v.y + v.z * v.z + v.w * v.w;
    }
    s += __shfl_xor(s, 1); s += __shfl_xor(s, 2);
    s2 += __shfl_xor(s2, 1); s2 += __shfl_xor(s2, 2);
    if (seg == 0) {
      float mn = s * (1.0f / 256.0f);
      mrow[row] = mn;
      rrow[row] = rsqrtf(s2 * (1.0f / 256.0f) - mn * mn + 1e-5f);
    }
  }
  __syncthreads();

  // staging assignment: row = tid&127, k-subchunk = tid>>7 (8 elems)
  int srow = tid & 127, skc = tid >> 7;
  const float* abase = h + (size_t)(m0 + srow) * DD + skc * 8;
  const short* bbase = Bt + (size_t)(n0 + srow) * K + skc * 8;
  float mn = mrow[srow], rs = rrow[srow];

  f32x4 vzero = {0.f, 0.f, 0.f, 0.f};
  f32x4 acc[2][4];
#pragma unroll
  for (int i = 0; i < 2; ++i)
#pragma unroll
    for (int j = 0; j < 4; ++j) acc[i][j] = vzero;

  // prologue: stage tile 0 into buffer 0
  {
    float4 x0 = *(const float4*)(abase);
    float4 x1 = *(const float4*)(abase + 4);
    int kk = skc * 8;
    float4 g0 = *(const float4*)&gls[kk], g1 = *(const float4*)&gls[kk + 4];
    float4 b0 = *(const float4*)&bls[kk], b1 = *(const float4*)&bls[kk + 4];
    bf16x8 aw;
    aw[0] = f2bf((x0.x - mn) * rs * g0.x + b0.x);
    aw[1] = f2bf((x0.y - mn) * rs * g0.y + b0.y);
    aw[2] = f2bf((x0.z - mn) * rs * g0.z + b0.z);
    aw[3] = f2bf((x0.w - mn) * rs * g0.w + b0.w);
    aw[4] = f2bf((x1.x - mn) * rs * g1.x + b1.x);
    aw[5] = f2bf((x1.y - mn) * rs * g1.y + b1.y);
    aw[6] = f2bf((x1.z - mn) * rs * g1.z + b1.z);
    aw[7] = f2bf((x1.w - mn) * rs * g1.w + b1.w);
    *(bf16x8*)&As[0][tid * 8] = aw;
    gld16(bbase, &Bs[0][tid * 8]);
  }

  const int nIter = 8;  // K=256 / 32
  for (int it = 0; it < nIter; ++it) {
    int cur = it & 1;
    __builtin_amdgcn_s_waitcnt(0x0070);  // vmcnt(0) lgkmcnt(0)
    __syncthreads();
    bool pf = (it + 1 < nIter);
    float4 x0, x1;
    if (pf) {
      gld16(bbase + (it + 1) * 32, &Bs[cur ^ 1][tid * 8]);
      x0 = *(const float4*)(abase + (it + 1) * 32);
      x1 = *(const float4*)(abase + (it + 1) * 32 + 4);
    }
    bf16x8 af[2], bfr[4];
#pragma unroll
    for (int mt = 0; mt < 2; ++mt)
      af[mt] = *(const bf16x8*)&As[cur][(q * 128 + wm + mt * 16 + r) * 8];
#pragma unroll
    for (int nt = 0; nt < 4; ++nt)
      bfr[nt] = *(const bf16x8*)&Bs[cur][(q * 128 + wn + nt * 16 + r) * 8];
#pragma unroll
    for (int mt = 0; mt < 2; ++mt)
#pragma unroll
      for (int nt = 0; nt < 4; ++nt)
        acc[mt][nt] = __builtin_amdgcn_mfma_f32_16x16x32_bf16(bfr[nt], af[mt], acc[mt][nt], 0, 0, 0);
    if (pf) {
      int kk = (it + 1) * 32 + skc * 8;
      float4 g0 = *(const float4*)&gls[kk], g1 = *(const float4*)&gls[kk + 4];
      float4 b0 = *(const float4*)&bls[kk], b1 = *(const float4*)&bls[kk + 4];
      bf16x8 aw;
      aw[0] = f2bf((x0.x - mn) * rs * g0.x + b0.x);
      aw[1] = f2bf((x0.y - mn) * rs * g0.y + b0.y);
      aw[2] = f2bf((x0.z - mn) * rs * g0.z + b0.z);
      aw[3] = f2bf((x0.w - mn) * rs * g0.w + b0.w);
      aw[4] = f2bf((x1.x - mn) * rs * g1.x + b1.x);
      aw[5] = f2bf((x1.y - mn) * rs * g1.y + b1.y);
      aw[6] = f2bf((x1.z - mn) * rs * g1.z + b1.z);
      aw[7] = f2bf((x1.w - mn) * rs * g1.w + b1.w);
      *(bf16x8*)&As[cur ^ 1][tid * 8] = aw;
    }
  }

  // epilogue: m = wm+mt*16+r, n = wn+nt*16+q*4+[0..3]
  float4 bias4[4];
#pragma unroll
  for (int nt = 0; nt < 4; ++nt) bias4[nt] = *(const float4*)&bias[n0 + wn + nt * 16 + q * 4];
#pragma unroll
  for (int mt = 0; mt < 2; ++mt) {
    int m = m0 + wm + mt * 16 + r;
    size_t rowoff = (size_t)m * N + n0 + wn + q * 4;
#pragma unroll
    for (int nt = 0; nt < 4; ++nt) {
      f32x4 v = acc[mt][nt];
      v[0] += bias4[nt].x; v[1] += bias4[nt].y; v[2] += bias4[nt].z; v[3] += bias4[nt].w;
      if (epi == 0) {
        if (z < 2) { v[0] *= v[0]; v[1] *= v[1]; v[2] *= v[2]; v[3] *= v[3]; }
      } else {
#pragma unroll
        for (int e = 0; e < 4; ++e) v[e] = fast_gelu(v[e]);
      }
      short4 o; o.x = f2bf(v[0]); o.y = f2bf(v[1]); o.z = f2bf(v[2]); o.w = f2bf(v[3]);
      *(short4*)&outz[rowoff + nt * 16] = o;
    }
  }
}

// ---------------- plain GEMM (FFN-down): h += A @ BT^T + bias -----------------
__global__ __launch_bounds__(512) void gemm_plain(
    const short* __restrict__ A, const short* __restrict__ Bt,
    const float* __restrict__ bias, float* __restrict__ outf, int N, int K) {
  __shared__ __align__(16) short As[2][4096];
  __shared__ __align__(16) short Bs[2][4096];
  int m0 = blockIdx.x * 128, n0 = blockIdx.y * 128;
  int tid = threadIdx.x;
  int lane = tid & 63, w = tid >> 6;
  int q = lane >> 4, r = lane & 15;
  int wm = (w >> 1) * 32, wn = (w & 1) * 64;
  f32x4 vzero = {0.f, 0.f, 0.f, 0.f};
  f32x4 acc[2][4];
#pragma unroll
  for (int i = 0; i < 2; ++i)
#pragma unroll
    for (int j = 0; j < 4; ++j) acc[i][j] = vzero;

  int srow = tid & 127, skc = tid >> 7;
  const short* abase = A + (size_t)(m0 + srow) * K + skc * 8;
  const short* bbase = Bt + (size_t)(n0 + srow) * K + skc * 8;

  gld16(abase, &As[0][tid * 8]);
  gld16(bbase, &Bs[0][tid * 8]);

  int nIter = K >> 5;
  for (int it = 0; it < nIter; ++it) {
    int cur = it & 1;
    __builtin_amdgcn_s_waitcnt(0x0f70);  // vmcnt(0)
    __syncthreads();
    if (it + 1 < nIter) {
      gld16(abase + (it + 1) * 32, &As[cur ^ 1][tid * 8]);
      gld16(bbase + (it + 1) * 32, &Bs[cur ^ 1][tid * 8]);
    }
    bf16x8 af[2], bfr[4];
#pragma unroll
    for (int mt = 0; mt < 2; ++mt)
      af[mt] = *(const bf16x8*)&As[cur][(q * 128 + wm + mt * 16 + r) * 8];
#pragma unroll
    for (int nt = 0; nt < 4; ++nt)
      bfr[nt] = *(const bf16x8*)&Bs[cur][(q * 128 + wn + nt * 16 + r) * 8];
#pragma unroll
    for (int mt = 0; mt < 2; ++mt)
#pragma unroll
      for (int nt = 0; nt < 4; ++nt)
        acc[mt][nt] = __builtin_amdgcn_mfma_f32_16x16x32_bf16(bfr[nt], af[mt], acc[mt][nt], 0, 0, 0);
  }

  float4 bias4[4];
#pragma unroll
  for (int nt = 0; nt < 4; ++nt) bias4[nt] = *(const float4*)&bias[n0 + wn + nt * 16 + q * 4];
#pragma unroll
  for (int mt = 0; mt < 2; ++mt) {
    int m = m0 + wm + mt * 16 + r;
    size_t rowoff = (size_t)m * N + n0 + wn + q * 4;
#pragma unroll
    for (int nt = 0; nt < 4; ++nt) {
      f32x4 v = acc[mt][nt];
      float4 cur4 = *(float4*)&outf[rowoff + nt * 16];
      cur4.x += v[0] + bias4[nt].x; cur4.y += v[1] + bias4[nt].y;
      cur4.z += v[2] + bias4[nt].z; cur4.w += v[3] + bias4[nt].w;
      *(float4*)&outf[rowoff + nt * 16] = cur4;
    }
  }
}

// ---------------- attention A1: per (b,h,chunk) S_c = K^T V, z_c = sum k ------
__global__ __launch_bounds__(256) void attn_chunk_kv(
    const short* __restrict__ Kb, const short* __restrict__ Vb,
    float* __restrict__ St, float* __restrict__ Zc) {
  __shared__ short Kt[4][32 * 72];
  __shared__ short Vt[4][32 * 72];
  int wid = threadIdx.x >> 6;
  int blk = blockIdx.x * 4 + wid;
  int c = blk & (NC - 1), bh = blk >> 5;
  int b = bh >> 3, hh = bh & 7;
  int lane = threadIdx.x & 63, q = lane >> 4, r = lane & 15;
  size_t rowbase = ((size_t)(b * GG + c * CS + lane)) * DD + hh * 32;
#pragma unroll
  for (int j = 0; j < 4; ++j) {
    bf16x8 kv = *(const bf16x8*)&Kb[rowbase + j * 8];
    bf16x8 vv = *(const bf16x8*)&Vb[rowbase + j * 8];
#pragma unroll
    for (int e = 0; e < 8; ++e) {
      Kt[wid][(j * 8 + e) * 72 + lane] = kv[e];
      Vt[wid][(j * 8 + e) * 72 + lane] = vv[e];
    }
  }
  __syncthreads();
  f32x4 vzero = {0.f, 0.f, 0.f, 0.f};
  f32x4 acc[2][2];
#pragma unroll
  for (int i = 0; i < 2; ++i)
#pragma unroll
    for (int j = 0; j < 2; ++j) acc[i][j] = vzero;
#pragma unroll
  for (int ks = 0; ks < 2; ++ks) {
    bf16x8 afr[2], bfr[2];
#pragma unroll
    for (int mt = 0; mt < 2; ++mt) afr[mt] = *(const bf16x8*)&Kt[wid][(mt * 16 + r) * 72 + ks * 32 + q * 8];
#pragma unroll
    for (int nt = 0; nt < 2; ++nt) bfr[nt] = *(const bf16x8*)&Vt[wid][(nt * 16 + r) * 72 + ks * 32 + q * 8];
#pragma unroll
    for (int mt = 0; mt < 2; ++mt)
#pragma unroll
      for (int nt = 0; nt < 2; ++nt)
        acc[mt][nt] = __builtin_amdgcn_mfma_f32_16x16x32_bf16(afr[mt], bfr[nt], acc[mt][nt], 0, 0, 0);
  }
  float* stp = St + ((size_t)bh * NC + c) * 1024;
#pragma unroll
  for (int mt = 0; mt < 2; ++mt)
#pragma unroll
    for (int nt = 0; nt < 2; ++nt)
      *(f32x4*)&stp[(nt * 16 + r) * 32 + mt * 16 + q * 4] = acc[mt][nt];  // St[d][f]
  if (lane < 32) {
    float s = 0.f;
#pragma unroll
    for (int j = 0; j < 8; ++j) {
      bf16x8 kr = *(const bf16x8*)&Kt[wid][lane * 72 + j * 8];
#pragma unroll
      for (int e = 0; e < 8; ++e) s += bf2f(kr[e]);
    }
    Zc[((size_t)bh * NC + c) * 32 + lane] = s;
  }
}

// ---------------- attention A2: exclusive prefix over chunks ------------------
__global__ __launch_bounds__(1024) void attn_prefix(float* __restrict__ St, float* __restrict__ Zc) {
  int bh = blockIdx.x, i = threadIdx.x;
  float run = 0.f;
  float* p = St + (size_t)bh * NC * 1024 + i;
#pragma unroll
  for (int c = 0; c < NC; ++c) { float t = p[(size_t)c * 1024]; p[(size_t)c * 1024] = run; run += t; }
  if (i < 32) {
    float rz = 0.f;
    float* pz = Zc + (size_t)bh * NC * 32 + i;
#pragma unroll
    for (int c = 0; c < NC; ++c) { float t = pz[c * 32]; pz[c * 32] = rz; rz += t; }
  }
}

// ---------------- attention B: intra-chunk + apply, h += out ------------------
__global__ __launch_bounds__(256) void attn_intra(
    const short* __restrict__ Qb, const short* __restrict__ Kb,
    const short* __restrict__ Vb, const float* __restrict__ St,
    const float* __restrict__ Zc, float* __restrict__ h) {
  __shared__ short P[4][64 * 72];
  __shared__ short Vt[4][32 * 72];
  __shared__ float den[4][64];
  int wid = threadIdx.x >> 6;
  int blk = blockIdx.x * 4 + wid;
  int c = blk & (NC - 1), bh = blk >> 5;
  int b = bh >> 3, hh = bh & 7;
  int lane = threadIdx.x & 63, q = lane >> 4, r = lane & 15;
  size_t row0 = (size_t)b * GG + c * CS;

  const float* zp = Zc + ((size_t)bh * NC + c) * 32;
  float qz = 0.f;
  {
    size_t qoff = (row0 + lane) * DD + hh * 32;
#pragma unroll
    for (int j = 0; j < 4; ++j) {
      bf16x8 qv = *(const bf16x8*)&Qb[qoff + j * 8];
#pragma unroll
      for (int e = 0; e < 8; ++e) qz += bf2f(qv[e]) * zp[j * 8 + e];
    }
  }
  den[wid][lane] = qz;

  {
    size_t voff = (row0 + lane) * DD + hh * 32;
#pragma unroll
    for (int j = 0; j < 4; ++j) {
      bf16x8 vv = *(const bf16x8*)&Vb[voff + j * 8];
#pragma unroll
      for (int e = 0; e < 8; ++e) Vt[wid][(j * 8 + e) * 72 + lane] = vv[e];
    }
  }

  bf16x8 ak[4], bqf[4];
#pragma unroll
  for (int t4 = 0; t4 < 4; ++t4) {
    ak[t4]  = *(const bf16x8*)&Kb[(row0 + t4 * 16 + r) * DD + hh * 32 + q * 8];
    bqf[t4] = *(const bf16x8*)&Qb[(row0 + t4 * 16 + r) * DD + hh * 32 + q * 8];
  }
  f32x4 vzero = {0.f, 0.f, 0.f, 0.f};
  f32x4 pacc[4][4];
#pragma unroll
  for (int mt = 0; mt < 4; ++mt)
#pragma unroll
    for (int nt = 0; nt < 4; ++nt)
      pacc[mt][nt] = __builtin_amdgcn_mfma_f32_16x16x32_bf16(ak[mt], bqf[nt], vzero, 0, 0, 0);

  float rs[4] = {0.f, 0.f, 0.f, 0.f};
#pragma unroll
  for (int nt = 0; nt < 4; ++nt) {
    int t = nt * 16 + r;
#pragma unroll
    for (int mt = 0; mt < 4; ++mt) {
      short4 pk;
#pragma unroll
      for (int rr = 0; rr < 4; ++rr) {
        int s = mt * 16 + q * 4 + rr;
        float pv = (s <= t) ? pacc[mt][nt][rr] : 0.f;
        rs[nt] += pv;
        ((short*)&pk)[rr] = f2bf(pv);
      }
      *(short4*)&P[wid][t * 72 + mt * 16 + q * 4] = pk;
    }
  }
#pragma unroll
  for (int nt = 0; nt < 4; ++nt) {
    rs[nt] += __shfl_xor(rs[nt], 16);
    rs[nt] += __shfl_xor(rs[nt], 32);
  }
  __syncthreads();
  if (lane < 16) {
#pragma unroll
    for (int nt = 0; nt < 4; ++nt) den[wid][nt * 16 + lane] += rs[nt];
  }
  __syncthreads();

  f32x4 oacc[4][2];
#pragma unroll
  for (int mt = 0; mt < 4; ++mt)
#pragma unroll
    for (int nt2 = 0; nt2 < 2; ++nt2) oacc[mt][nt2] = vzero;
  const float* stp = St + ((size_t)bh * NC + c) * 1024;
#pragma unroll
  for (int nt2 = 0; nt2 < 2; ++nt2) {
    float4 s0 = *(const float4*)&stp[(nt2 * 16 + r) * 32 + q * 8];
    float4 s1 = *(const float4*)&stp[(nt2 * 16 + r) * 32 + q * 8 + 4];
    bf16x8 bs;
    bs[0] = f2bf(s0.x); bs[1] = f2bf(s0.y); bs[2] = f2bf(s0.z); bs[3] = f2bf(s0.w);
    bs[4] = f2bf(s1.x); bs[5] = f2bf(s1.y); bs[6] = f2bf(s1.z); bs[7] = f2bf(s1.w);
#pragma unroll
    for (int mt = 0; mt < 4; ++mt)
      oacc[mt][nt2] = __builtin_amdgcn_mfma_f32_16x16x32_bf16(bqf[mt], bs, oacc[mt][nt2], 0, 0, 0);
  }
#pragma unroll
  for (int ks = 0; ks < 2; ++ks) {
    bf16x8 ap[4];
#pragma unroll
    for (int mt = 0; mt < 4; ++mt)
      ap[mt] = *(const bf16x8*)&P[wid][(mt * 16 + r) * 72 + ks * 32 + q * 8];
#pragma unroll
    for (int nt2 = 0; nt2 < 2; ++nt2) {
      bf16x8 bv_ = *(const bf16x8*)&Vt[wid][(nt2 * 16 + r) * 72 + ks * 32 + q * 8];
#pragma unroll
      for (int mt = 0; mt < 4; ++mt)
        oacc[mt][nt2] = __builtin_amdgcn_mfma_f32_16x16x32_bf16(ap[mt], bv_, oacc[mt][nt2], 0, 0, 0);
    }
  }

#pragma unroll
  for (int mt = 0; mt < 4; ++mt) {
#pragma unroll
    for (int rr = 0; rr < 4; ++rr) {
      int t = mt * 16 + q * 4 + rr;
      float inv = 1.0f / (den[wid][t] + 1e-16f);
#pragma unroll
      for (int nt2 = 0; nt2 < 2; ++nt2) {
        int d = nt2 * 16 + r;
        size_t off = (row0 + t) * DD + hh * 32 + d;
        h[off] += oacc[mt][nt2][rr] * inv;
      }
    }
  }
}

// ---------------- final projection -------------------------------------------
__global__ __launch_bounds__(256) void out_proj(
    const float* __restrict__ h, const float* __restrict__ Wout,
    const float* __restrict__ bout, float* __restrict__ out) {
  int row = blockIdx.x * 4 + (threadIdx.x >> 6);
  int lane = threadIdx.x & 63;
  float4 a = *(const float4*)&h[(size_t)row * DD + lane * 4];
  float4 w = *(const float4*)&Wout[lane * 4];
  float s = a.x * w.x + a.y * w.y + a.z * w.z + a.w * w.w;
#pragma unroll
  for (int o = 1; o < 64; o <<= 1) s += __shfl_xor(s, o);
  if (lane == 0) out[row] = s + bout[0];
}

extern "C" void kernel_launch(void* const* d_in, const int* in_sizes, int n_in,
                              void* d_out, int out_size, void* d_ws, size_t ws_size,
                              hipStream_t stream) {
  const float* x    = (const float*)d_in[0];
  const float* ge   = (const float*)d_in[1];
  const float* invf = (const float*)d_in[2];
  const float* Wq   = (const float*)d_in[3];
  const float* bq   = (const float*)d_in[4];
  const float* Wk   = (const float*)d_in[5];
  const float* bk   = (const float*)d_in[6];
  const float* Wv   = (const float*)d_in[7];
  const float* bv   = (const float*)d_in[8];
  const float* ln1g = (const float*)d_in[9];
  const float* ln1b = (const float*)d_in[10];
  const float* ln2g = (const float*)d_in[11];
  const float* ln2b = (const float*)d_in[12];
  const float* WU   = (const float*)d_in[13];
  const float* bU   = (const float*)d_in[14];
  const float* WV   = (const float*)d_in[15];
  const float* bV   = (const float*)d_in[16];
  const float* Wout = (const float*)d_in[17];
  const float* bout = (const float*)d_in[18];
  float* out = (float*)d_out;

  char* ws = (char*)d_ws;
  float* h   = (float*)(ws + 0);            // 33.5 MB
  char*  R   = ws + 50331648;               // shared region
  short* qb  = (short*)(R + 0);
  short* kb  = (short*)(R + 16777216);
  short* vb  = (short*)(R + 33554432);
  float* St  = (float*)(R + 50331648);
  float* Zc  = (float*)(R + 67108864);
  short* mid = (short*)(ws + 0x4000000 + 67633152 - 67108864);  // placed below
  char*  WT  = R + 67633152;
  short* TQ  = (short*)(WT + 0);
  short* TK  = (short*)(WT + 524288);
  short* TVq = (short*)(WT + 1048576);
  short* TU  = (short*)(WT + 1572864);
  short* TVd = (short*)(WT + 3670016);
  // mid (FFN activations, 67.1 MB bf16) overlaps q/k/v region in time:
  mid = (short*)(R + 0);

  prep_weights<<<dim3(1024, 4, 5), 256, 0, stream>>>(Wq, Wk, Wv, WU, WV, TQ, TK, TVq, TU, TVd);
  embed_kernel<<<NROWS / 4, 256, 0, stream>>>(x, ge, invf, h);

  for (int l = 0; l < 4; ++l) {
    lngemm<<<dim3(256, 2, 3), 512, 0, stream>>>(
        h, TQ + l * 65536, TK + l * 65536, TVq + l * 65536,
        ln1g + l * 256, ln1b + l * 256,
        bq + l * 256, bk + l * 256, bv + l * 256,
        qb, kb, vb, 256, 0);
    attn_chunk_kv<<<1024, 256, 0, stream>>>(kb, vb, St, Zc);
    attn_prefix<<<128, 1024, 0, stream>>>(St, Zc);
    attn_intra<<<1024, 256, 0, stream>>>(qb, kb, vb, St, Zc, h);
    lngemm<<<dim3(256, 8, 1), 512, 0, stream>>>(
        h, TU + l * 262144, nullptr, nullptr,
        ln2g + l * 256, ln2b + l * 256,
        bU + l * 1024, nullptr, nullptr,
        mid, nullptr, nullptr, 1024, 1);
    gemm_plain<<<dim3(256, 2), 512, 0, stream>>>(
        mid, TVd + l * 262144, bV + l * 256, h, 256, 1024);
  }
  out_proj<<<NROWS / 4, 256, 0, stream>>>(h, Wout, bout, out);
}

// Round 6
// 950.045 us; speedup vs baseline: 1.2285x; 1.2285x over previous
//
#include <hip/hip_runtime.h>
#include <math.h>

// ExpressionPerformer: B=16,G=2048,D=256,H=8,dh=32,FFN=1024,L=4
// Round-6:
//  - revert R5 LN-fusion (fp32 re-reads + VALU in loop regressed); ln_kernel back.
//  - gemm: TRUE rolling pipeline. 3 LDS buffers, raw s_barrier (no compiler
//    vmcnt(0) drain), s_waitcnt vmcnt(8) drains only the oldest load-group.
//    R2/R3/R4 all had vmcnt(0)+__syncthreads -> zero loads in flight across
//    barriers; this is the AITER-style fix (m139 validated raw-barrier pattern).

#define GG 2048
#define DD 256
#define NROWS 32768
#define NC 32
#define CS 64

typedef __attribute__((ext_vector_type(8))) short bf16x8;
typedef __attribute__((ext_vector_type(4))) float f32x4;

__device__ __forceinline__ short f2bf(float f) {
  union { float f; unsigned u; } v; v.f = f;
  unsigned r = v.u + 0x7FFFu + ((v.u >> 16) & 1u);
  return (short)(r >> 16);
}
__device__ __forceinline__ float bf2f(short s) {
  union { unsigned u; float f; } v; v.u = ((unsigned)(unsigned short)s) << 16;
  return v.f;
}
__device__ __forceinline__ void gld16(const short* g, short* l) {
  __builtin_amdgcn_global_load_lds(
      (const __attribute__((address_space(1))) void*)g,
      (__attribute__((address_space(3))) void*)l, 16, 0, 0);
}
__device__ __forceinline__ float fast_gelu(float x) {
  float y = 1.595769122f * (x + 0.044715f * x * x * x);
  return x / (1.0f + __expf(-y));
}

// ---------------- embed ------------------------------------------------------
__global__ __launch_bounds__(256) void embed_kernel(
    const float* __restrict__ x, const float* __restrict__ ge,
    const float* __restrict__ invf, float* __restrict__ h) {
  int bg = blockIdx.x * 4 + (threadIdx.x >> 6);
  int g = bg & (GG - 1);
  int lane = threadIdx.x & 63;
  float xv = x[bg];
  int d = lane * 4;
  float4 e;
  if (lane < 32) {
    float4 f = *(const float4*)&invf[d];
    e.x = sinf(xv * f.x); e.y = sinf(xv * f.y);
    e.z = sinf(xv * f.z); e.w = sinf(xv * f.w);
  } else {
    float4 f = *(const float4*)&invf[d - 128];
    e.x = cosf(xv * f.x); e.y = cosf(xv * f.y);
    e.z = cosf(xv * f.z); e.w = cosf(xv * f.w);
  }
  if (xv == -10.0f) { e.x = 0.f; e.y = 0.f; e.z = 0.f; e.w = 0.f; }
  float4 gv = *(const float4*)&ge[(size_t)g * DD + d];
  float4 o; o.x = gv.x + e.x; o.y = gv.y + e.y; o.z = gv.z + e.z; o.w = gv.w + e.w;
  *(float4*)&h[(size_t)bg * DD + d] = o;
}

// ---------------- layernorm (row of 256) -> bf16, 4 rows/block ----------------
__global__ __launch_bounds__(256) void ln_kernel(
    const float* __restrict__ h, const float* __restrict__ gamma,
    const float* __restrict__ beta, short* __restrict__ out) {
  int row = blockIdx.x * 4 + (threadIdx.x >> 6);
  int lane = threadIdx.x & 63;
  float4 xv = *(const float4*)&h[(size_t)row * DD + lane * 4];
  float s = xv.x + xv.y + xv.z + xv.w;
#pragma unroll
  for (int o = 1; o < 64; o <<= 1) s += __shfl_xor(s, o);
  float mean = s * (1.0f / 256.0f);
  float a = xv.x - mean, b = xv.y - mean, c = xv.z - mean, d = xv.w - mean;
  float s2 = a * a + b * b + c * c + d * d;
#pragma unroll
  for (int o = 1; o < 64; o <<= 1) s2 += __shfl_xor(s2, o);
  float rstd = rsqrtf(s2 * (1.0f / 256.0f) + 1e-5f);
  float4 g = *(const float4*)&gamma[lane * 4];
  float4 bb = *(const float4*)&beta[lane * 4];
  short4 o4;
  o4.x = f2bf(a * rstd * g.x + bb.x);
  o4.y = f2bf(b * rstd * g.y + bb.y);
  o4.z = f2bf(c * rstd * g.z + bb.z);
  o4.w = f2bf(d * rstd * g.w + bb.w);
  *(short4*)&out[(size_t)row * DD + lane * 4] = o4;
}

// ---------------- weight convert+transpose -----------------------------------
__global__ __launch_bounds__(256) void prep_weights(
    const float* __restrict__ Wq, const float* __restrict__ Wk,
    const float* __restrict__ Wv, const float* __restrict__ WU,
    const float* __restrict__ WV,
    short* __restrict__ TQ, short* __restrict__ TK, short* __restrict__ TV,
    short* __restrict__ TU, short* __restrict__ TVd) {
  int zz = blockIdx.z, l = blockIdx.y;
  const float* src; short* dst; int Kd, Nd;
  if (zz == 0) { src = Wq; dst = TQ; Kd = 256; Nd = 256; }
  else if (zz == 1) { src = Wk; dst = TK; Kd = 256; Nd = 256; }
  else if (zz == 2) { src = Wv; dst = TV; Kd = 256; Nd = 256; }
  else if (zz == 3) { src = WU; dst = TU; Kd = 256; Nd = 1024; }
  else { src = WV; dst = TVd; Kd = 1024; Nd = 256; }
  int tot = Kd * Nd;
  int e = blockIdx.x * 256 + threadIdx.x;
  if (e >= tot) return;
  int n = e / Kd, k = e - n * Kd;
  dst[(size_t)l * tot + e] = f2bf(src[(size_t)l * tot + (size_t)k * Nd + n]);
}

// ---------------- bf16 MFMA GEMM: C = A[M,K] * BT[N,K]^T + bias ---------------
// 3-buffer rolling pipeline, raw barriers, vmcnt(8) oldest-group drain.
// epi 0: z<2 -> square, bf16 out (QKV); 1: fast gelu, bf16 out; 2: h += acc+bias
__global__ __launch_bounds__(256) void gemm_bf16(
    const short* __restrict__ A, const short* __restrict__ B0,
    const short* __restrict__ B1, const short* __restrict__ B2,
    const float* __restrict__ bias0, const float* __restrict__ bias1,
    const float* __restrict__ bias2,
    short* __restrict__ o0, short* __restrict__ o1, short* __restrict__ o2,
    float* __restrict__ outf, int N, int K, int epi) {
  __shared__ __align__(16) short As[3][4096];  // 128m x 32k, chunk-major
  __shared__ __align__(16) short Bs[3][4096];  // 128n x 32k
  int z = blockIdx.z;
  const short* Bt = (z == 0) ? B0 : (z == 1) ? B1 : B2;
  const float* bias = (z == 0) ? bias0 : (z == 1) ? bias1 : bias2;
  short* outz = (z == 0) ? o0 : (z == 1) ? o1 : o2;
  int m0 = blockIdx.x * 128, n0 = blockIdx.y * 128;
  int tid = threadIdx.x;
  int lane = tid & 63, w = tid >> 6;
  int q = lane >> 4, r = lane & 15;
  int wm = (w >> 1) * 64, wn = (w & 1) * 64;
  f32x4 vzero = {0.f, 0.f, 0.f, 0.f};
  f32x4 acc[4][4];
#pragma unroll
  for (int i = 0; i < 4; ++i)
#pragma unroll
    for (int j = 0; j < 4; ++j) acc[i][j] = vzero;

  int c0 = tid, c1 = tid + 256;
  const short* a0 = &A[(size_t)(m0 + (c0 & 127)) * K + (c0 >> 7) * 8];
  const short* a1 = &A[(size_t)(m0 + (c1 & 127)) * K + (c1 >> 7) * 8];
  const short* b0p = &Bt[(size_t)(n0 + (c0 & 127)) * K + (c0 >> 7) * 8];
  const short* b1p = &Bt[(size_t)(n0 + (c1 & 127)) * K + (c1 >> 7) * 8];

  int nIter = K >> 5;
  // prologue: issue groups 0,1,2 (4 loads each per thread -> 12 outstanding)
#pragma unroll
  for (int g = 0; g < 3; ++g) {
    gld16(a0 + g * 32, &As[g][c0 * 8]);
    gld16(a1 + g * 32, &As[g][c1 * 8]);
    gld16(b0p + g * 32, &Bs[g][c0 * 8]);
    gld16(b1p + g * 32, &Bs[g][c1 * 8]);
  }

  int cur = 0;
  for (int it = 0; it < nIter; ++it) {
    // drain ONLY the oldest group (group `it`): 4*min(nIter-1-it, 2) left in flight
    if (it + 2 < nIter)      __builtin_amdgcn_s_waitcnt(0x0f78);  // vmcnt(8)
    else if (it + 2 == nIter) __builtin_amdgcn_s_waitcnt(0x0f74); // vmcnt(4)
    else                      __builtin_amdgcn_s_waitcnt(0x0f70); // vmcnt(0)
    __builtin_amdgcn_s_barrier();  // group `it` landed for all waves

    bf16x8 af[4], bfr[4];
#pragma unroll
    for (int mt = 0; mt < 4; ++mt)
      af[mt] = *(const bf16x8*)&As[cur][(q * 128 + wm + mt * 16 + r) * 8];
#pragma unroll
    for (int nt = 0; nt < 4; ++nt)
      bfr[nt] = *(const bf16x8*)&Bs[cur][(q * 128 + wn + nt * 16 + r) * 8];
#pragma unroll
    for (int mt = 0; mt < 4; ++mt)
#pragma unroll
      for (int nt = 0; nt < 4; ++nt)
        acc[mt][nt] = __builtin_amdgcn_mfma_f32_16x16x32_bf16(bfr[nt], af[mt], acc[mt][nt], 0, 0, 0);

    __builtin_amdgcn_s_waitcnt(0xc07f);  // lgkmcnt(0): my ds_reads consumed
    __builtin_amdgcn_s_barrier();        // all waves done reading buf `cur`
    if (it + 3 < nIter) {                // refill buf `cur` with group it+3
      int kn = (it + 3) * 32;
      gld16(a0 + kn, &As[cur][c0 * 8]);
      gld16(a1 + kn, &As[cur][c1 * 8]);
      gld16(b0p + kn, &Bs[cur][c0 * 8]);
      gld16(b1p + kn, &Bs[cur][c1 * 8]);
    }
    cur = (cur == 2) ? 0 : cur + 1;
  }

  // epilogue: lane (q,r) tile (mt,nt): m = wm+mt*16+r, n = wn+nt*16+q*4+[0..3]
  float4 bias4[4];
#pragma unroll
  for (int nt = 0; nt < 4; ++nt) bias4[nt] = *(const float4*)&bias[n0 + wn + nt * 16 + q * 4];
#pragma unroll
  for (int mt = 0; mt < 4; ++mt) {
    int m = m0 + wm + mt * 16 + r;
    size_t rowoff = (size_t)m * N + n0 + wn + q * 4;
#pragma unroll
    for (int nt = 0; nt < 4; ++nt) {
      f32x4 v = acc[mt][nt];
      v[0] += bias4[nt].x; v[1] += bias4[nt].y; v[2] += bias4[nt].z; v[3] += bias4[nt].w;
      if (epi == 0) {
        if (z < 2) { v[0] *= v[0]; v[1] *= v[1]; v[2] *= v[2]; v[3] *= v[3]; }
        short4 o; o.x = f2bf(v[0]); o.y = f2bf(v[1]); o.z = f2bf(v[2]); o.w = f2bf(v[3]);
        *(short4*)&outz[rowoff + nt * 16] = o;
      } else if (epi == 1) {
#pragma unroll
        for (int e = 0; e < 4; ++e) v[e] = fast_gelu(v[e]);
        short4 o; o.x = f2bf(v[0]); o.y = f2bf(v[1]); o.z = f2bf(v[2]); o.w = f2bf(v[3]);
        *(short4*)&outz[rowoff + nt * 16] = o;
      } else {
        float4 cur4 = *(float4*)&outf[rowoff + nt * 16];
        cur4.x += v[0]; cur4.y += v[1]; cur4.z += v[2]; cur4.w += v[3];
        *(float4*)&outf[rowoff + nt * 16] = cur4;
      }
    }
  }
}

// ---------------- attention A1: per (b,h,chunk) S_c = K^T V, z_c = sum k ------
__global__ __launch_bounds__(256) void attn_chunk_kv(
    const short* __restrict__ Kb, const short* __restrict__ Vb,
    float* __restrict__ St, float* __restrict__ Zc) {
  __shared__ short Kt[4][32 * 72];
  __shared__ short Vt[4][32 * 72];
  int wid = threadIdx.x >> 6;
  int blk = blockIdx.x * 4 + wid;
  int c = blk & (NC - 1), bh = blk >> 5;
  int b = bh >> 3, hh = bh & 7;
  int lane = threadIdx.x & 63, q = lane >> 4, r = lane & 15;
  size_t rowbase = ((size_t)(b * GG + c * CS + lane)) * DD + hh * 32;
#pragma unroll
  for (int j = 0; j < 4; ++j) {
    bf16x8 kv = *(const bf16x8*)&Kb[rowbase + j * 8];
    bf16x8 vv = *(const bf16x8*)&Vb[rowbase + j * 8];
#pragma unroll
    for (int e = 0; e < 8; ++e) {
      Kt[wid][(j * 8 + e) * 72 + lane] = kv[e];
      Vt[wid][(j * 8 + e) * 72 + lane] = vv[e];
    }
  }
  __syncthreads();
  f32x4 vzero = {0.f, 0.f, 0.f, 0.f};
  f32x4 acc[2][2];
#pragma unroll
  for (int i = 0; i < 2; ++i)
#pragma unroll
    for (int j = 0; j < 2; ++j) acc[i][j] = vzero;
#pragma unroll
  for (int ks = 0; ks < 2; ++ks) {
    bf16x8 afr[2], bfr[2];
#pragma unroll
    for (int mt = 0; mt < 2; ++mt) afr[mt] = *(const bf16x8*)&Kt[wid][(mt * 16 + r) * 72 + ks * 32 + q * 8];
#pragma unroll
    for (int nt = 0; nt < 2; ++nt) bfr[nt] = *(const bf16x8*)&Vt[wid][(nt * 16 + r) * 72 + ks * 32 + q * 8];
#pragma unroll
    for (int mt = 0; mt < 2; ++mt)
#pragma unroll
      for (int nt = 0; nt < 2; ++nt)
        acc[mt][nt] = __builtin_amdgcn_mfma_f32_16x16x32_bf16(afr[mt], bfr[nt], acc[mt][nt], 0, 0, 0);
  }
  float* stp = St + ((size_t)bh * NC + c) * 1024;
#pragma unroll
  for (int mt = 0; mt < 2; ++mt)
#pragma unroll
    for (int nt = 0; nt < 2; ++nt)
      *(f32x4*)&stp[(nt * 16 + r) * 32 + mt * 16 + q * 4] = acc[mt][nt];  // St[d][f]
  if (lane < 32) {
    float s = 0.f;
#pragma unroll
    for (int j = 0; j < 8; ++j) {
      bf16x8 kr = *(const bf16x8*)&Kt[wid][lane * 72 + j * 8];
#pragma unroll
      for (int e = 0; e < 8; ++e) s += bf2f(kr[e]);
    }
    Zc[((size_t)bh * NC + c) * 32 + lane] = s;
  }
}

// ---------------- attention A2: exclusive prefix over chunks ------------------
__global__ __launch_bounds__(1024) void attn_prefix(float* __restrict__ St, float* __restrict__ Zc) {
  int bh = blockIdx.x, i = threadIdx.x;
  float run = 0.f;
  float* p = St + (size_t)bh * NC * 1024 + i;
#pragma unroll
  for (int c = 0; c < NC; ++c) { float t = p[(size_t)c * 1024]; p[(size_t)c * 1024] = run; run += t; }
  if (i < 32) {
    float rz = 0.f;
    float* pz = Zc + (size_t)bh * NC * 32 + i;
#pragma unroll
    for (int c = 0; c < NC; ++c) { float t = pz[c * 32]; pz[c * 32] = rz; rz += t; }
  }
}

// ---------------- attention B: intra-chunk + apply, h += out ------------------
__global__ __launch_bounds__(256) void attn_intra(
    const short* __restrict__ Qb, const short* __restrict__ Kb,
    const short* __restrict__ Vb, const float* __restrict__ St,
    const float* __restrict__ Zc, float* __restrict__ h) {
  __shared__ short P[4][64 * 72];
  __shared__ short Vt[4][32 * 72];
  __shared__ float den[4][64];
  int wid = threadIdx.x >> 6;
  int blk = blockIdx.x * 4 + wid;
  int c = blk & (NC - 1), bh = blk >> 5;
  int b = bh >> 3, hh = bh & 7;
  int lane = threadIdx.x & 63, q = lane >> 4, r = lane & 15;
  size_t row0 = (size_t)b * GG + c * CS;

  const float* zp = Zc + ((size_t)bh * NC + c) * 32;
  float qz = 0.f;
  {
    size_t qoff = (row0 + lane) * DD + hh * 32;
#pragma unroll
    for (int j = 0; j < 4; ++j) {
      bf16x8 qv = *(const bf16x8*)&Qb[qoff + j * 8];
#pragma unroll
      for (int e = 0; e < 8; ++e) qz += bf2f(qv[e]) * zp[j * 8 + e];
    }
  }
  den[wid][lane] = qz;

  {
    size_t voff = (row0 + lane) * DD + hh * 32;
#pragma unroll
    for (int j = 0; j < 4; ++j) {
      bf16x8 vv = *(const bf16x8*)&Vb[voff + j * 8];
#pragma unroll
      for (int e = 0; e < 8; ++e) Vt[wid][(j * 8 + e) * 72 + lane] = vv[e];
    }
  }

  bf16x8 ak[4], bqf[4];
#pragma unroll
  for (int t4 = 0; t4 < 4; ++t4) {
    ak[t4]  = *(const bf16x8*)&Kb[(row0 + t4 * 16 + r) * DD + hh * 32 + q * 8];
    bqf[t4] = *(const bf16x8*)&Qb[(row0 + t4 * 16 + r) * DD + hh * 32 + q * 8];
  }
  f32x4 vzero = {0.f, 0.f, 0.f, 0.f};
  f32x4 pacc[4][4];
#pragma unroll
  for (int mt = 0; mt < 4; ++mt)
#pragma unroll
    for (int nt = 0; nt < 4; ++nt)
      pacc[mt][nt] = __builtin_amdgcn_mfma_f32_16x16x32_bf16(ak[mt], bqf[nt], vzero, 0, 0, 0);

  float rs[4] = {0.f, 0.f, 0.f, 0.f};
#pragma unroll
  for (int nt = 0; nt < 4; ++nt) {
    int t = nt * 16 + r;
#pragma unroll
    for (int mt = 0; mt < 4; ++mt) {
      short4 pk;
#pragma unroll
      for (int rr = 0; rr < 4; ++rr) {
        int s = mt * 16 + q * 4 + rr;
        float pv = (s <= t) ? pacc[mt][nt][rr] : 0.f;
        rs[nt] += pv;
        ((short*)&pk)[rr] = f2bf(pv);
      }
      *(short4*)&P[wid][t * 72 + mt * 16 + q * 4] = pk;
    }
  }
#pragma unroll
  for (int nt = 0; nt < 4; ++nt) {
    rs[nt] += __shfl_xor(rs[nt], 16);
    rs[nt] += __shfl_xor(rs[nt], 32);
  }
  __syncthreads();
  if (lane < 16) {
#pragma unroll
    for (int nt = 0; nt < 4; ++nt) den[wid][nt * 16 + lane] += rs[nt];
  }
  __syncthreads();

  f32x4 oacc[4][2];
#pragma unroll
  for (int mt = 0; mt < 4; ++mt)
#pragma unroll
    for (int nt2 = 0; nt2 < 2; ++nt2) oacc[mt][nt2] = vzero;
  const float* stp = St + ((size_t)bh * NC + c) * 1024;
#pragma unroll
  for (int nt2 = 0; nt2 < 2; ++nt2) {
    float4 s0 = *(const float4*)&stp[(nt2 * 16 + r) * 32 + q * 8];
    float4 s1 = *(const float4*)&stp[(nt2 * 16 + r) * 32 + q * 8 + 4];
    bf16x8 bs;
    bs[0] = f2bf(s0.x); bs[1] = f2bf(s0.y); bs[2] = f2bf(s0.z); bs[3] = f2bf(s0.w);
    bs[4] = f2bf(s1.x); bs[5] = f2bf(s1.y); bs[6] = f2bf(s1.z); bs[7] = f2bf(s1.w);
#pragma unroll
    for (int mt = 0; mt < 4; ++mt)
      oacc[mt][nt2] = __builtin_amdgcn_mfma_f32_16x16x32_bf16(bqf[mt], bs, oacc[mt][nt2], 0, 0, 0);
  }
#pragma unroll
  for (int ks = 0; ks < 2; ++ks) {
    bf16x8 ap[4];
#pragma unroll
    for (int mt = 0; mt < 4; ++mt)
      ap[mt] = *(const bf16x8*)&P[wid][(mt * 16 + r) * 72 + ks * 32 + q * 8];
#pragma unroll
    for (int nt2 = 0; nt2 < 2; ++nt2) {
      bf16x8 bv_ = *(const bf16x8*)&Vt[wid][(nt2 * 16 + r) * 72 + ks * 32 + q * 8];
#pragma unroll
      for (int mt = 0; mt < 4; ++mt)
        oacc[mt][nt2] = __builtin_amdgcn_mfma_f32_16x16x32_bf16(ap[mt], bv_, oacc[mt][nt2], 0, 0, 0);
    }
  }

#pragma unroll
  for (int mt = 0; mt < 4; ++mt) {
#pragma unroll
    for (int rr = 0; rr < 4; ++rr) {
      int t = mt * 16 + q * 4 + rr;
      float inv = 1.0f / (den[wid][t] + 1e-16f);
#pragma unroll
      for (int nt2 = 0; nt2 < 2; ++nt2) {
        int d = nt2 * 16 + r;
        size_t off = (row0 + t) * DD + hh * 32 + d;
        h[off] += oacc[mt][nt2][rr] * inv;
      }
    }
  }
}

// ---------------- final projection -------------------------------------------
__global__ __launch_bounds__(256) void out_proj(
    const float* __restrict__ h, const float* __restrict__ Wout,
    const float* __restrict__ bout, float* __restrict__ out) {
  int row = blockIdx.x * 4 + (threadIdx.x >> 6);
  int lane = threadIdx.x & 63;
  float4 a = *(const float4*)&h[(size_t)row * DD + lane * 4];
  float4 w = *(const float4*)&Wout[lane * 4];
  float s = a.x * w.x + a.y * w.y + a.z * w.z + a.w * w.w;
#pragma unroll
  for (int o = 1; o < 64; o <<= 1) s += __shfl_xor(s, o);
  if (lane == 0) out[row] = s + bout[0];
}

extern "C" void kernel_launch(void* const* d_in, const int* in_sizes, int n_in,
                              void* d_out, int out_size, void* d_ws, size_t ws_size,
                              hipStream_t stream) {
  const float* x    = (const float*)d_in[0];
  const float* ge   = (const float*)d_in[1];
  const float* invf = (const float*)d_in[2];
  const float* Wq   = (const float*)d_in[3];
  const float* bq   = (const float*)d_in[4];
  const float* Wk   = (const float*)d_in[5];
  const float* bk   = (const float*)d_in[6];
  const float* Wv   = (const float*)d_in[7];
  const float* bv   = (const float*)d_in[8];
  const float* ln1g = (const float*)d_in[9];
  const float* ln1b = (const float*)d_in[10];
  const float* ln2g = (const float*)d_in[11];
  const float* ln2b = (const float*)d_in[12];
  const float* WU   = (const float*)d_in[13];
  const float* bU   = (const float*)d_in[14];
  const float* WV   = (const float*)d_in[15];
  const float* bV   = (const float*)d_in[16];
  const float* Wout = (const float*)d_in[17];
  const float* bout = (const float*)d_in[18];
  float* out = (float*)d_out;

  char* ws = (char*)d_ws;
  float* h   = (float*)(ws + 0);            // 33.5 MB
  short* hn  = (short*)(ws + 33554432);     // 16.8 MB
  char*  R   = ws + 50331648;               // shared region
  short* qb  = (short*)(R + 0);
  short* kb  = (short*)(R + 16777216);
  short* vb  = (short*)(R + 33554432);
  float* St  = (float*)(R + 50331648);
  float* Zc  = (float*)(R + 67108864);
  short* mid = (short*)(R + 0);             // FFN phase (overlaps q/k/v in time)
  char*  WT  = R + 67633152;
  short* TQ  = (short*)(WT + 0);
  short* TK  = (short*)(WT + 524288);
  short* TVq = (short*)(WT + 1048576);
  short* TU  = (short*)(WT + 1572864);
  short* TVd = (short*)(WT + 3670016);

  prep_weights<<<dim3(1024, 4, 5), 256, 0, stream>>>(Wq, Wk, Wv, WU, WV, TQ, TK, TVq, TU, TVd);
  embed_kernel<<<NROWS / 4, 256, 0, stream>>>(x, ge, invf, h);

  for (int l = 0; l < 4; ++l) {
    ln_kernel<<<NROWS / 4, 256, 0, stream>>>(h, ln1g + l * 256, ln1b + l * 256, hn);
    gemm_bf16<<<dim3(256, 2, 3), 256, 0, stream>>>(
        hn, TQ + l * 65536, TK + l * 65536, TVq + l * 65536,
        bq + l * 256, bk + l * 256, bv + l * 256,
        qb, kb, vb, nullptr, 256, 256, 0);
    attn_chunk_kv<<<1024, 256, 0, stream>>>(kb, vb, St, Zc);
    attn_prefix<<<128, 1024, 0, stream>>>(St, Zc);
    attn_intra<<<1024, 256, 0, stream>>>(qb, kb, vb, St, Zc, h);
    ln_kernel<<<NROWS / 4, 256, 0, stream>>>(h, ln2g + l * 256, ln2b + l * 256, hn);
    gemm_bf16<<<dim3(256, 8, 1), 256, 0, stream>>>(
        hn, TU + l * 262144, nullptr, nullptr,
        bU + l * 1024, nullptr, nullptr,
        mid, nullptr, nullptr, nullptr, 1024, 256, 1);
    gemm_bf16<<<dim3(256, 2, 1), 256, 0, stream>>>(
        mid, TVd + l * 262144, nullptr, nullptr,
        bV + l * 256, nullptr, nullptr,
        nullptr, nullptr, nullptr, h, 256, 1024, 2);
  }
  out_proj<<<NROWS / 4, 256, 0, stream>>>(h, Wout, bout, out);
}

// Round 7
// 802.640 us; speedup vs baseline: 1.4541x; 1.1837x over previous
//
#include <hip/hip_runtime.h>
#include <math.h>

// ExpressionPerformer: B=16,G=2048,D=256,H=8,dh=32,FFN=1024,L=4
// Round-7: TILED OPERAND LAYOUTS. R2-R6 staging read 16B per lane from 64
// different rows (64 cache lines per load instr, 8x L2 request amplification)
// -> request-rate-bound at ~65us/gemm regardless of pipelining. Now every
// 128x32 GEMM tile is a contiguous 8KB block in global memory, identical to
// its LDS image [kc8][row][8]; staging is gld16(tile + tid*16B) -> each wave
// reads 1KB contiguous. hn (ln output), all weights, and mid (FFN activation)
// are stored tiled. Rolling 3-buffer pipeline from R6 kept.

#define GG 2048
#define DD 256
#define NROWS 32768
#define NC 32
#define CS 64

typedef __attribute__((ext_vector_type(8))) short bf16x8;
typedef __attribute__((ext_vector_type(4))) float f32x4;

__device__ __forceinline__ short f2bf(float f) {
  union { float f; unsigned u; } v; v.f = f;
  unsigned r = v.u + 0x7FFFu + ((v.u >> 16) & 1u);
  return (short)(r >> 16);
}
__device__ __forceinline__ float bf2f(short s) {
  union { unsigned u; float f; } v; v.u = ((unsigned)(unsigned short)s) << 16;
  return v.f;
}
__device__ __forceinline__ void gld16(const short* g, short* l) {
  __builtin_amdgcn_global_load_lds(
      (const __attribute__((address_space(1))) void*)g,
      (__attribute__((address_space(3))) void*)l, 16, 0, 0);
}
__device__ __forceinline__ float fast_gelu(float x) {
  float y = 1.595769122f * (x + 0.044715f * x * x * x);
  return x / (1.0f + __expf(-y));
}

// ---------------- embed ------------------------------------------------------
__global__ __launch_bounds__(256) void embed_kernel(
    const float* __restrict__ x, const float* __restrict__ ge,
    const float* __restrict__ invf, float* __restrict__ h) {
  int bg = blockIdx.x * 4 + (threadIdx.x >> 6);
  int g = bg & (GG - 1);
  int lane = threadIdx.x & 63;
  float xv = x[bg];
  int d = lane * 4;
  float4 e;
  if (lane < 32) {
    float4 f = *(const float4*)&invf[d];
    e.x = sinf(xv * f.x); e.y = sinf(xv * f.y);
    e.z = sinf(xv * f.z); e.w = sinf(xv * f.w);
  } else {
    float4 f = *(const float4*)&invf[d - 128];
    e.x = cosf(xv * f.x); e.y = cosf(xv * f.y);
    e.z = cosf(xv * f.z); e.w = cosf(xv * f.w);
  }
  if (xv == -10.0f) { e.x = 0.f; e.y = 0.f; e.z = 0.f; e.w = 0.f; }
  float4 gv = *(const float4*)&ge[(size_t)g * DD + d];
  float4 o; o.x = gv.x + e.x; o.y = gv.y + e.y; o.z = gv.z + e.z; o.w = gv.w + e.w;
  *(float4*)&h[(size_t)bg * DD + d] = o;
}

// ---------------- layernorm -> TILED bf16 ------------------------------------
// block = 32 rows; out tile layout: tile(mt,kb)=8KB block, cslot=[kc8*128+row]*8
__global__ __launch_bounds__(256) void ln_tiled(
    const float* __restrict__ h, const float* __restrict__ gamma,
    const float* __restrict__ beta, short* __restrict__ outT) {
  __shared__ float mean_s[32], rstd_s[32];
  __shared__ float gls[256], bls[256];
  int r0 = blockIdx.x * 32;
  int tid = threadIdx.x;
  gls[tid] = gamma[tid]; bls[tid] = beta[tid];
  {
    int row = tid >> 3, seg = tid & 7;
    const float4* hp = (const float4*)(h + (size_t)(r0 + row) * DD + seg * 32);
    float s = 0.f, s2 = 0.f;
#pragma unroll
    for (int i = 0; i < 8; ++i) {
      float4 v = hp[i];
      s += v.x + v.y + v.z + v.w;
      s2 += v.x * v.x + v.y * v.y + v.z * v.z + v.w * v.w;
    }
    s += __shfl_xor(s, 1); s += __shfl_xor(s, 2); s += __shfl_xor(s, 4);
    s2 += __shfl_xor(s2, 1); s2 += __shfl_xor(s2, 2); s2 += __shfl_xor(s2, 4);
    if (seg == 0) {
      float mn = s * (1.0f / 256.0f);
      mean_s[row] = mn;
      rstd_s[row] = rsqrtf(s2 * (1.0f / 256.0f) - mn * mn + 1e-5f);
    }
  }
  __syncthreads();
  int row = tid & 31, kc8 = (tid >> 5) & 3, half = tid >> 7;
  float mn = mean_s[row], rs = rstd_s[row];
  size_t hrow = (size_t)(r0 + row) * DD;
  int trow = (r0 & 127) + row;
  short* tb = outT + (size_t)(r0 >> 7) * 8 * 4096 + (kc8 * 128 + trow) * 8;
#pragma unroll
  for (int j = 0; j < 4; ++j) {
    int kb = half * 4 + j;
    int k0 = kb * 32 + kc8 * 8;
    float4 x0 = *(const float4*)&h[hrow + k0];
    float4 x1 = *(const float4*)&h[hrow + k0 + 4];
    float4 g0 = *(const float4*)&gls[k0], g1 = *(const float4*)&gls[k0 + 4];
    float4 b0 = *(const float4*)&bls[k0], b1 = *(const float4*)&bls[k0 + 4];
    bf16x8 aw;
    aw[0] = f2bf((x0.x - mn) * rs * g0.x + b0.x);
    aw[1] = f2bf((x0.y - mn) * rs * g0.y + b0.y);
    aw[2] = f2bf((x0.z - mn) * rs * g0.z + b0.z);
    aw[3] = f2bf((x0.w - mn) * rs * g0.w + b0.w);
    aw[4] = f2bf((x1.x - mn) * rs * g1.x + b1.x);
    aw[5] = f2bf((x1.y - mn) * rs * g1.y + b1.y);
    aw[6] = f2bf((x1.z - mn) * rs * g1.z + b1.z);
    aw[7] = f2bf((x1.w - mn) * rs * g1.w + b1.w);
    *(bf16x8*)&tb[(size_t)kb * 4096] = aw;
  }
}

// ---------------- weight convert+transpose -> TILED --------------------------
// dst-linear enumeration: e indexes tiled layout; coalesced writes.
__global__ __launch_bounds__(256) void prep_weights(
    const float* __restrict__ Wq, const float* __restrict__ Wk,
    const float* __restrict__ Wv, const float* __restrict__ WU,
    const float* __restrict__ WV,
    short* __restrict__ TQ, short* __restrict__ TK, short* __restrict__ TV,
    short* __restrict__ TU, short* __restrict__ TVd) {
  int zz = blockIdx.z, l = blockIdx.y;
  const float* src; short* dst; int Kd, Nd;
  if (zz == 0) { src = Wq; dst = TQ; Kd = 256; Nd = 256; }
  else if (zz == 1) { src = Wk; dst = TK; Kd = 256; Nd = 256; }
  else if (zz == 2) { src = Wv; dst = TV; Kd = 256; Nd = 256; }
  else if (zz == 3) { src = WU; dst = TU; Kd = 256; Nd = 1024; }
  else { src = WV; dst = TVd; Kd = 1024; Nd = 256; }
  int tot = Kd * Nd;
  int e = blockIdx.x * 256 + threadIdx.x;
  if (e >= tot) return;
  int t = e >> 12;
  int cslot = (e >> 3) & 511;
  int elem = e & 7;
  int kc8 = cslot >> 7, rn = cslot & 127;
  int nKb = Kd >> 5;
  int nt = t / nKb, kb = t - nt * nKb;
  int n = nt * 128 + rn, k = kb * 32 + kc8 * 8 + elem;
  dst[(size_t)l * tot + e] = f2bf(src[(size_t)l * tot + (size_t)k * Nd + n]);
}

// ---------------- bf16 MFMA GEMM (tiled operands) -----------------------------
// A,Bt tiled: tile(rt,kb) = 8KB contiguous. Rolling 3-buffer pipeline (R6).
// epi 0: z<2 square, row-major bf16 out; 1: gelu, TILED bf16 out; 2: h += +bias
__global__ __launch_bounds__(256) void gemm_bf16(
    const short* __restrict__ A, const short* __restrict__ B0,
    const short* __restrict__ B1, const short* __restrict__ B2,
    const float* __restrict__ bias0, const float* __restrict__ bias1,
    const float* __restrict__ bias2,
    short* __restrict__ o0, short* __restrict__ o1, short* __restrict__ o2,
    float* __restrict__ outf, int N, int K, int epi) {
  __shared__ __align__(16) short As[3][4096];
  __shared__ __align__(16) short Bs[3][4096];
  int z = blockIdx.z;
  const short* Bt = (z == 0) ? B0 : (z == 1) ? B1 : B2;
  const float* bias = (z == 0) ? bias0 : (z == 1) ? bias1 : bias2;
  short* outz = (z == 0) ? o0 : (z == 1) ? o1 : o2;
  int m0 = blockIdx.x * 128, n0 = blockIdx.y * 128;
  int tid = threadIdx.x;
  int lane = tid & 63, w = tid >> 6;
  int q = lane >> 4, r = lane & 15;
  int wm = (w >> 1) * 64, wn = (w & 1) * 64;
  int nKb = K >> 5;
  const short* At = A + (size_t)blockIdx.x * nKb * 4096;
  const short* Btl = Bt + (size_t)blockIdx.y * nKb * 4096;
  f32x4 vzero = {0.f, 0.f, 0.f, 0.f};
  f32x4 acc[4][4];
#pragma unroll
  for (int i = 0; i < 4; ++i)
#pragma unroll
    for (int j = 0; j < 4; ++j) acc[i][j] = vzero;

  int c0 = tid * 8, c1 = (tid + 256) * 8;
  // prologue: groups 0,1,2 (4 loads each per thread -> 12 outstanding)
#pragma unroll
  for (int g = 0; g < 3; ++g) {
    gld16(At + g * 4096 + c0, &As[g][c0]);
    gld16(At + g * 4096 + c1, &As[g][c1]);
    gld16(Btl + g * 4096 + c0, &Bs[g][c0]);
    gld16(Btl + g * 4096 + c1, &Bs[g][c1]);
  }

  int nIter = nKb;
  int cur = 0;
  for (int it = 0; it < nIter; ++it) {
    if (it + 2 < nIter)       __builtin_amdgcn_s_waitcnt(0x0f78);  // vmcnt(8)
    else if (it + 2 == nIter) __builtin_amdgcn_s_waitcnt(0x0f74);  // vmcnt(4)
    else                      __builtin_amdgcn_s_waitcnt(0x0f70);  // vmcnt(0)
    __builtin_amdgcn_s_barrier();

    bf16x8 af[4], bfr[4];
#pragma unroll
    for (int mt = 0; mt < 4; ++mt)
      af[mt] = *(const bf16x8*)&As[cur][(q * 128 + wm + mt * 16 + r) * 8];
#pragma unroll
    for (int nt = 0; nt < 4; ++nt)
      bfr[nt] = *(const bf16x8*)&Bs[cur][(q * 128 + wn + nt * 16 + r) * 8];
#pragma unroll
    for (int mt = 0; mt < 4; ++mt)
#pragma unroll
      for (int nt = 0; nt < 4; ++nt)
        acc[mt][nt] = __builtin_amdgcn_mfma_f32_16x16x32_bf16(bfr[nt], af[mt], acc[mt][nt], 0, 0, 0);

    __builtin_amdgcn_s_waitcnt(0xc07f);  // lgkmcnt(0)
    __builtin_amdgcn_s_barrier();
    if (it + 3 < nIter) {
      size_t kn = (size_t)(it + 3) * 4096;
      gld16(At + kn + c0, &As[cur][c0]);
      gld16(At + kn + c1, &As[cur][c1]);
      gld16(Btl + kn + c0, &Bs[cur][c0]);
      gld16(Btl + kn + c1, &Bs[cur][c1]);
    }
    cur = (cur == 2) ? 0 : cur + 1;
  }

  // epilogue: m = m0+wm+mt*16+r, n = n0+wn+nt*16+q*4+[0..3]
  float4 bias4[4];
#pragma unroll
  for (int nt = 0; nt < 4; ++nt) bias4[nt] = *(const float4*)&bias[n0 + wn + nt * 16 + q * 4];
#pragma unroll
  for (int mt = 0; mt < 4; ++mt) {
    int ml = wm + mt * 16 + r;            // m & 127
    int m = m0 + ml;
    size_t rowoff = (size_t)m * N + n0 + wn + q * 4;
#pragma unroll
    for (int nt = 0; nt < 4; ++nt) {
      f32x4 v = acc[mt][nt];
      v[0] += bias4[nt].x; v[1] += bias4[nt].y; v[2] += bias4[nt].z; v[3] += bias4[nt].w;
      if (epi == 0) {
        if (z < 2) { v[0] *= v[0]; v[1] *= v[1]; v[2] *= v[2]; v[3] *= v[3]; }
        short4 o; o.x = f2bf(v[0]); o.y = f2bf(v[1]); o.z = f2bf(v[2]); o.w = f2bf(v[3]);
        *(short4*)&outz[rowoff + nt * 16] = o;
      } else if (epi == 1) {
#pragma unroll
        for (int e = 0; e < 4; ++e) v[e] = fast_gelu(v[e]);
        short4 o; o.x = f2bf(v[0]); o.y = f2bf(v[1]); o.z = f2bf(v[2]); o.w = f2bf(v[3]);
        int n = n0 + wn + nt * 16 + q * 4;
        size_t ti = ((size_t)blockIdx.x * (N >> 5) + (n >> 5)) * 4096 +
                    (size_t)(((n >> 3) & 3) << 10) + (ml << 3) + (n & 7);
        *(short4*)&outz[ti] = o;
      } else {
        float4 cur4 = *(float4*)&outf[rowoff + nt * 16];
        cur4.x += v[0]; cur4.y += v[1]; cur4.z += v[2]; cur4.w += v[3];
        *(float4*)&outf[rowoff + nt * 16] = cur4;
      }
    }
  }
}

// ---------------- attention A1: per (b,h,chunk) S_c = K^T V, z_c = sum k ------
__global__ __launch_bounds__(256) void attn_chunk_kv(
    const short* __restrict__ Kb, const short* __restrict__ Vb,
    float* __restrict__ St, float* __restrict__ Zc) {
  __shared__ short Kt[4][32 * 72];
  __shared__ short Vt[4][32 * 72];
  int wid = threadIdx.x >> 6;
  int blk = blockIdx.x * 4 + wid;
  int c = blk & (NC - 1), bh = blk >> 5;
  int b = bh >> 3, hh = bh & 7;
  int lane = threadIdx.x & 63, q = lane >> 4, r = lane & 15;
  size_t rowbase = ((size_t)(b * GG + c * CS + lane)) * DD + hh * 32;
#pragma unroll
  for (int j = 0; j < 4; ++j) {
    bf16x8 kv = *(const bf16x8*)&Kb[rowbase + j * 8];
    bf16x8 vv = *(const bf16x8*)&Vb[rowbase + j * 8];
#pragma unroll
    for (int e = 0; e < 8; ++e) {
      Kt[wid][(j * 8 + e) * 72 + lane] = kv[e];
      Vt[wid][(j * 8 + e) * 72 + lane] = vv[e];
    }
  }
  __syncthreads();
  f32x4 vzero = {0.f, 0.f, 0.f, 0.f};
  f32x4 acc[2][2];
#pragma unroll
  for (int i = 0; i < 2; ++i)
#pragma unroll
    for (int j = 0; j < 2; ++j) acc[i][j] = vzero;
#pragma unroll
  for (int ks = 0; ks < 2; ++ks) {
    bf16x8 afr[2], bfr[2];
#pragma unroll
    for (int mt = 0; mt < 2; ++mt) afr[mt] = *(const bf16x8*)&Kt[wid][(mt * 16 + r) * 72 + ks * 32 + q * 8];
#pragma unroll
    for (int nt = 0; nt < 2; ++nt) bfr[nt] = *(const bf16x8*)&Vt[wid][(nt * 16 + r) * 72 + ks * 32 + q * 8];
#pragma unroll
    for (int mt = 0; mt < 2; ++mt)
#pragma unroll
      for (int nt = 0; nt < 2; ++nt)
        acc[mt][nt] = __builtin_amdgcn_mfma_f32_16x16x32_bf16(afr[mt], bfr[nt], acc[mt][nt], 0, 0, 0);
  }
  float* stp = St + ((size_t)bh * NC + c) * 1024;
#pragma unroll
  for (int mt = 0; mt < 2; ++mt)
#pragma unroll
    for (int nt = 0; nt < 2; ++nt)
      *(f32x4*)&stp[(nt * 16 + r) * 32 + mt * 16 + q * 4] = acc[mt][nt];  // St[d][f]
  if (lane < 32) {
    float s = 0.f;
#pragma unroll
    for (int j = 0; j < 8; ++j) {
      bf16x8 kr = *(const bf16x8*)&Kt[wid][lane * 72 + j * 8];
#pragma unroll
      for (int e = 0; e < 8; ++e) s += bf2f(kr[e]);
    }
    Zc[((size_t)bh * NC + c) * 32 + lane] = s;
  }
}

// ---------------- attention A2: exclusive prefix over chunks ------------------
__global__ __launch_bounds__(1024) void attn_prefix(float* __restrict__ St, float* __restrict__ Zc) {
  int bh = blockIdx.x, i = threadIdx.x;
  float run = 0.f;
  float* p = St + (size_t)bh * NC * 1024 + i;
#pragma unroll
  for (int c = 0; c < NC; ++c) { float t = p[(size_t)c * 1024]; p[(size_t)c * 1024] = run; run += t; }
  if (i < 32) {
    float rz = 0.f;
    float* pz = Zc + (size_t)bh * NC * 32 + i;
#pragma unroll
    for (int c = 0; c < NC; ++c) { float t = pz[c * 32]; pz[c * 32] = rz; rz += t; }
  }
}

// ---------------- attention B: intra-chunk + apply, h += out ------------------
__global__ __launch_bounds__(256) void attn_intra(
    const short* __restrict__ Qb, const short* __restrict__ Kb,
    const short* __restrict__ Vb, const float* __restrict__ St,
    const float* __restrict__ Zc, float* __restrict__ h) {
  __shared__ short P[4][64 * 72];
  __shared__ short Vt[4][32 * 72];
  __shared__ float den[4][64];
  int wid = threadIdx.x >> 6;
  int blk = blockIdx.x * 4 + wid;
  int c = blk & (NC - 1), bh = blk >> 5;
  int b = bh >> 3, hh = bh & 7;
  int lane = threadIdx.x & 63, q = lane >> 4, r = lane & 15;
  size_t row0 = (size_t)b * GG + c * CS;

  const float* zp = Zc + ((size_t)bh * NC + c) * 32;
  float qz = 0.f;
  {
    size_t qoff = (row0 + lane) * DD + hh * 32;
#pragma unroll
    for (int j = 0; j < 4; ++j) {
      bf16x8 qv = *(const bf16x8*)&Qb[qoff + j * 8];
#pragma unroll
      for (int e = 0; e < 8; ++e) qz += bf2f(qv[e]) * zp[j * 8 + e];
    }
  }
  den[wid][lane] = qz;

  {
    size_t voff = (row0 + lane) * DD + hh * 32;
#pragma unroll
    for (int j = 0; j < 4; ++j) {
      bf16x8 vv = *(const bf16x8*)&Vb[voff + j * 8];
#pragma unroll
      for (int e = 0; e < 8; ++e) Vt[wid][(j * 8 + e) * 72 + lane] = vv[e];
    }
  }

  bf16x8 ak[4], bqf[4];
#pragma unroll
  for (int t4 = 0; t4 < 4; ++t4) {
    ak[t4]  = *(const bf16x8*)&Kb[(row0 + t4 * 16 + r) * DD + hh * 32 + q * 8];
    bqf[t4] = *(const bf16x8*)&Qb[(row0 + t4 * 16 + r) * DD + hh * 32 + q * 8];
  }
  f32x4 vzero = {0.f, 0.f, 0.f, 0.f};
  f32x4 pacc[4][4];
#pragma unroll
  for (int mt = 0; mt < 4; ++mt)
#pragma unroll
    for (int nt = 0; nt < 4; ++nt)
      pacc[mt][nt] = __builtin_amdgcn_mfma_f32_16x16x32_bf16(ak[mt], bqf[nt], vzero, 0, 0, 0);

  float rs[4] = {0.f, 0.f, 0.f, 0.f};
#pragma unroll
  for (int nt = 0; nt < 4; ++nt) {
    int t = nt * 16 + r;
#pragma unroll
    for (int mt = 0; mt < 4; ++mt) {
      short4 pk;
#pragma unroll
      for (int rr = 0; rr < 4; ++rr) {
        int s = mt * 16 + q * 4 + rr;
        float pv = (s <= t) ? pacc[mt][nt][rr] : 0.f;
        rs[nt] += pv;
        ((short*)&pk)[rr] = f2bf(pv);
      }
      *(short4*)&P[wid][t * 72 + mt * 16 + q * 4] = pk;
    }
  }
#pragma unroll
  for (int nt = 0; nt < 4; ++nt) {
    rs[nt] += __shfl_xor(rs[nt], 16);
    rs[nt] += __shfl_xor(rs[nt], 32);
  }
  __syncthreads();
  if (lane < 16) {
#pragma unroll
    for (int nt = 0; nt < 4; ++nt) den[wid][nt * 16 + lane] += rs[nt];
  }
  __syncthreads();

  f32x4 oacc[4][2];
#pragma unroll
  for (int mt = 0; mt < 4; ++mt)
#pragma unroll
    for (int nt2 = 0; nt2 < 2; ++nt2) oacc[mt][nt2] = vzero;
  const float* stp = St + ((size_t)bh * NC + c) * 1024;
#pragma unroll
  for (int nt2 = 0; nt2 < 2; ++nt2) {
    float4 s0 = *(const float4*)&stp[(nt2 * 16 + r) * 32 + q * 8];
    float4 s1 = *(const float4*)&stp[(nt2 * 16 + r) * 32 + q * 8 + 4];
    bf16x8 bs;
    bs[0] = f2bf(s0.x); bs[1] = f2bf(s0.y); bs[2] = f2bf(s0.z); bs[3] = f2bf(s0.w);
    bs[4] = f2bf(s1.x); bs[5] = f2bf(s1.y); bs[6] = f2bf(s1.z); bs[7] = f2bf(s1.w);
#pragma unroll
    for (int mt = 0; mt < 4; ++mt)
      oacc[mt][nt2] = __builtin_amdgcn_mfma_f32_16x16x32_bf16(bqf[mt], bs, oacc[mt][nt2], 0, 0, 0);
  }
#pragma unroll
  for (int ks = 0; ks < 2; ++ks) {
    bf16x8 ap[4];
#pragma unroll
    for (int mt = 0; mt < 4; ++mt)
      ap[mt] = *(const bf16x8*)&P[wid][(mt * 16 + r) * 72 + ks * 32 + q * 8];
#pragma unroll
    for (int nt2 = 0; nt2 < 2; ++nt2) {
      bf16x8 bv_ = *(const bf16x8*)&Vt[wid][(nt2 * 16 + r) * 72 + ks * 32 + q * 8];
#pragma unroll
      for (int mt = 0; mt < 4; ++mt)
        oacc[mt][nt2] = __builtin_amdgcn_mfma_f32_16x16x32_bf16(ap[mt], bv_, oacc[mt][nt2], 0, 0, 0);
    }
  }

#pragma unroll
  for (int mt = 0; mt < 4; ++mt) {
#pragma unroll
    for (int rr = 0; rr < 4; ++rr) {
      int t = mt * 16 + q * 4 + rr;
      float inv = 1.0f / (den[wid][t] + 1e-16f);
#pragma unroll
      for (int nt2 = 0; nt2 < 2; ++nt2) {
        int d = nt2 * 16 + r;
        size_t off = (row0 + t) * DD + hh * 32 + d;
        h[off] += oacc[mt][nt2][rr] * inv;
      }
    }
  }
}

// ---------------- final projection -------------------------------------------
__global__ __launch_bounds__(256) void out_proj(
    const float* __restrict__ h, const float* __restrict__ Wout,
    const float* __restrict__ bout, float* __restrict__ out) {
  int row = blockIdx.x * 4 + (threadIdx.x >> 6);
  int lane = threadIdx.x & 63;
  float4 a = *(const float4*)&h[(size_t)row * DD + lane * 4];
  float4 w = *(const float4*)&Wout[lane * 4];
  float s = a.x * w.x + a.y * w.y + a.z * w.z + a.w * w.w;
#pragma unroll
  for (int o = 1; o < 64; o <<= 1) s += __shfl_xor(s, o);
  if (lane == 0) out[row] = s + bout[0];
}

extern "C" void kernel_launch(void* const* d_in, const int* in_sizes, int n_in,
                              void* d_out, int out_size, void* d_ws, size_t ws_size,
                              hipStream_t stream) {
  const float* x    = (const float*)d_in[0];
  const float* ge   = (const float*)d_in[1];
  const float* invf = (const float*)d_in[2];
  const float* Wq   = (const float*)d_in[3];
  const float* bq   = (const float*)d_in[4];
  const float* Wk   = (const float*)d_in[5];
  const float* bk   = (const float*)d_in[6];
  const float* Wv   = (const float*)d_in[7];
  const float* bv   = (const float*)d_in[8];
  const float* ln1g = (const float*)d_in[9];
  const float* ln1b = (const float*)d_in[10];
  const float* ln2g = (const float*)d_in[11];
  const float* ln2b = (const float*)d_in[12];
  const float* WU   = (const float*)d_in[13];
  const float* bU   = (const float*)d_in[14];
  const float* WV   = (const float*)d_in[15];
  const float* bV   = (const float*)d_in[16];
  const float* Wout = (const float*)d_in[17];
  const float* bout = (const float*)d_in[18];
  float* out = (float*)d_out;

  char* ws = (char*)d_ws;
  float* h   = (float*)(ws + 0);            // 33.5 MB
  short* hn  = (short*)(ws + 33554432);     // 16.8 MB (tiled)
  char*  R   = ws + 50331648;               // shared region
  short* qb  = (short*)(R + 0);
  short* kb  = (short*)(R + 16777216);
  short* vb  = (short*)(R + 33554432);
  float* St  = (float*)(R + 50331648);
  float* Zc  = (float*)(R + 67108864);
  short* mid = (short*)(R + 0);             // FFN phase (tiled, overlaps q/k/v)
  char*  WT  = R + 67633152;
  short* TQ  = (short*)(WT + 0);
  short* TK  = (short*)(WT + 524288);
  short* TVq = (short*)(WT + 1048576);
  short* TU  = (short*)(WT + 1572864);
  short* TVd = (short*)(WT + 3670016);

  prep_weights<<<dim3(1024, 4, 5), 256, 0, stream>>>(Wq, Wk, Wv, WU, WV, TQ, TK, TVq, TU, TVd);
  embed_kernel<<<NROWS / 4, 256, 0, stream>>>(x, ge, invf, h);

  for (int l = 0; l < 4; ++l) {
    ln_tiled<<<NROWS / 32, 256, 0, stream>>>(h, ln1g + l * 256, ln1b + l * 256, hn);
    gemm_bf16<<<dim3(256, 2, 3), 256, 0, stream>>>(
        hn, TQ + l * 65536, TK + l * 65536, TVq + l * 65536,
        bq + l * 256, bk + l * 256, bv + l * 256,
        qb, kb, vb, nullptr, 256, 256, 0);
    attn_chunk_kv<<<1024, 256, 0, stream>>>(kb, vb, St, Zc);
    attn_prefix<<<128, 1024, 0, stream>>>(St, Zc);
    attn_intra<<<1024, 256, 0, stream>>>(qb, kb, vb, St, Zc, h);
    ln_tiled<<<NROWS / 32, 256, 0, stream>>>(h, ln2g + l * 256, ln2b + l * 256, hn);
    gemm_bf16<<<dim3(256, 8, 1), 256, 0, stream>>>(
        hn, TU + l * 262144, nullptr, nullptr,
        bU + l * 1024, nullptr, nullptr,
        mid, nullptr, nullptr, nullptr, 1024, 256, 1);
    gemm_bf16<<<dim3(256, 2, 1), 256, 0, stream>>>(
        mid, TVd + l * 262144, nullptr, nullptr,
        bV + l * 256, nullptr, nullptr,
        nullptr, nullptr, nullptr, h, 256, 1024, 2);
  }
  out_proj<<<NROWS / 4, 256, 0, stream>>>(h, Wout, bout, out);
}

// Round 8
// 790.313 us; speedup vs baseline: 1.4768x; 1.0156x over previous
//
#include <hip/hip_runtime.h>
#include <math.h>

// ExpressionPerformer: B=16,G=2048,D=256,H=8,dh=32,FFN=1024,L=4
// Round-8: templated GEMM (compile-time K, epi). Fully unrolled K-loop
// (runtime trip count in R7 blocked unrolling -> per-iter branch+addr VALU),
// 2-buffer 32KB LDS (5 blocks/CU vs 3 with R7's 48KB), rolling vmcnt(4)
// drain with compile-time parity. Tiled operand layouts from R7 kept.

#define GG 2048
#define DD 256
#define NROWS 32768
#define NC 32
#define CS 64

typedef __attribute__((ext_vector_type(8))) short bf16x8;
typedef __attribute__((ext_vector_type(4))) float f32x4;

__device__ __forceinline__ short f2bf(float f) {
  union { float f; unsigned u; } v; v.f = f;
  unsigned r = v.u + 0x7FFFu + ((v.u >> 16) & 1u);
  return (short)(r >> 16);
}
__device__ __forceinline__ float bf2f(short s) {
  union { unsigned u; float f; } v; v.u = ((unsigned)(unsigned short)s) << 16;
  return v.f;
}
__device__ __forceinline__ void gld16(const short* g, short* l) {
  __builtin_amdgcn_global_load_lds(
      (const __attribute__((address_space(1))) void*)g,
      (__attribute__((address_space(3))) void*)l, 16, 0, 0);
}
__device__ __forceinline__ float fast_gelu(float x) {
  float y = 1.595769122f * (x + 0.044715f * x * x * x);
  return x / (1.0f + __expf(-y));
}

// ---------------- embed ------------------------------------------------------
__global__ __launch_bounds__(256) void embed_kernel(
    const float* __restrict__ x, const float* __restrict__ ge,
    const float* __restrict__ invf, float* __restrict__ h) {
  int bg = blockIdx.x * 4 + (threadIdx.x >> 6);
  int g = bg & (GG - 1);
  int lane = threadIdx.x & 63;
  float xv = x[bg];
  int d = lane * 4;
  float4 e;
  if (lane < 32) {
    float4 f = *(const float4*)&invf[d];
    e.x = sinf(xv * f.x); e.y = sinf(xv * f.y);
    e.z = sinf(xv * f.z); e.w = sinf(xv * f.w);
  } else {
    float4 f = *(const float4*)&invf[d - 128];
    e.x = cosf(xv * f.x); e.y = cosf(xv * f.y);
    e.z = cosf(xv * f.z); e.w = cosf(xv * f.w);
  }
  if (xv == -10.0f) { e.x = 0.f; e.y = 0.f; e.z = 0.f; e.w = 0.f; }
  float4 gv = *(const float4*)&ge[(size_t)g * DD + d];
  float4 o; o.x = gv.x + e.x; o.y = gv.y + e.y; o.z = gv.z + e.z; o.w = gv.w + e.w;
  *(float4*)&h[(size_t)bg * DD + d] = o;
}

// ---------------- layernorm -> TILED bf16 ------------------------------------
__global__ __launch_bounds__(256) void ln_tiled(
    const float* __restrict__ h, const float* __restrict__ gamma,
    const float* __restrict__ beta, short* __restrict__ outT) {
  __shared__ float mean_s[32], rstd_s[32];
  __shared__ float gls[256], bls[256];
  int r0 = blockIdx.x * 32;
  int tid = threadIdx.x;
  gls[tid] = gamma[tid]; bls[tid] = beta[tid];
  {
    int row = tid >> 3, seg = tid & 7;
    const float4* hp = (const float4*)(h + (size_t)(r0 + row) * DD + seg * 32);
    float s = 0.f, s2 = 0.f;
#pragma unroll
    for (int i = 0; i < 8; ++i) {
      float4 v = hp[i];
      s += v.x + v.y + v.z + v.w;
      s2 += v.x * v.x + v.y * v.y + v.z * v.z + v.w * v.w;
    }
    s += __shfl_xor(s, 1); s += __shfl_xor(s, 2); s += __shfl_xor(s, 4);
    s2 += __shfl_xor(s2, 1); s2 += __shfl_xor(s2, 2); s2 += __shfl_xor(s2, 4);
    if (seg == 0) {
      float mn = s * (1.0f / 256.0f);
      mean_s[row] = mn;
      rstd_s[row] = rsqrtf(s2 * (1.0f / 256.0f) - mn * mn + 1e-5f);
    }
  }
  __syncthreads();
  int row = tid & 31, kc8 = (tid >> 5) & 3, half = tid >> 7;
  float mn = mean_s[row], rs = rstd_s[row];
  size_t hrow = (size_t)(r0 + row) * DD;
  int trow = (r0 & 127) + row;
  short* tb = outT + (size_t)(r0 >> 7) * 8 * 4096 + (kc8 * 128 + trow) * 8;
#pragma unroll
  for (int j = 0; j < 4; ++j) {
    int kb = half * 4 + j;
    int k0 = kb * 32 + kc8 * 8;
    float4 x0 = *(const float4*)&h[hrow + k0];
    float4 x1 = *(const float4*)&h[hrow + k0 + 4];
    float4 g0 = *(const float4*)&gls[k0], g1 = *(const float4*)&gls[k0 + 4];
    float4 b0 = *(const float4*)&bls[k0], b1 = *(const float4*)&bls[k0 + 4];
    bf16x8 aw;
    aw[0] = f2bf((x0.x - mn) * rs * g0.x + b0.x);
    aw[1] = f2bf((x0.y - mn) * rs * g0.y + b0.y);
    aw[2] = f2bf((x0.z - mn) * rs * g0.z + b0.z);
    aw[3] = f2bf((x0.w - mn) * rs * g0.w + b0.w);
    aw[4] = f2bf((x1.x - mn) * rs * g1.x + b1.x);
    aw[5] = f2bf((x1.y - mn) * rs * g1.y + b1.y);
    aw[6] = f2bf((x1.z - mn) * rs * g1.z + b1.z);
    aw[7] = f2bf((x1.w - mn) * rs * g1.w + b1.w);
    *(bf16x8*)&tb[(size_t)kb * 4096] = aw;
  }
}

// ---------------- weight convert+transpose -> TILED --------------------------
__global__ __launch_bounds__(256) void prep_weights(
    const float* __restrict__ Wq, const float* __restrict__ Wk,
    const float* __restrict__ Wv, const float* __restrict__ WU,
    const float* __restrict__ WV,
    short* __restrict__ TQ, short* __restrict__ TK, short* __restrict__ TV,
    short* __restrict__ TU, short* __restrict__ TVd) {
  int zz = blockIdx.z, l = blockIdx.y;
  const float* src; short* dst; int Kd, Nd;
  if (zz == 0) { src = Wq; dst = TQ; Kd = 256; Nd = 256; }
  else if (zz == 1) { src = Wk; dst = TK; Kd = 256; Nd = 256; }
  else if (zz == 2) { src = Wv; dst = TV; Kd = 256; Nd = 256; }
  else if (zz == 3) { src = WU; dst = TU; Kd = 256; Nd = 1024; }
  else { src = WV; dst = TVd; Kd = 1024; Nd = 256; }
  int tot = Kd * Nd;
  int e = blockIdx.x * 256 + threadIdx.x;
  if (e >= tot) return;
  int t = e >> 12;
  int cslot = (e >> 3) & 511;
  int elem = e & 7;
  int kc8 = cslot >> 7, rn = cslot & 127;
  int nKb = Kd >> 5;
  int nt = t / nKb, kb = t - nt * nKb;
  int n = nt * 128 + rn, k = kb * 32 + kc8 * 8 + elem;
  dst[(size_t)l * tot + e] = f2bf(src[(size_t)l * tot + (size_t)k * Nd + n]);
}

// ---------------- bf16 MFMA GEMM (tiled operands, compile-time K) -------------
// 2-buffer rolling pipeline: at iter top outstanding={gi,gi+1}(8), vmcnt(4)
// drains group gi; lgkmcnt(0)+barrier covers WAR before refill of buf gi&1.
// EPI 0: z<2 square, row-major bf16 out; 1: gelu, TILED out; 2: h += acc+bias
template <int K, int EPI>
__global__ __launch_bounds__(256) void gemm_t(
    const short* __restrict__ A, const short* __restrict__ B0,
    const short* __restrict__ B1, const short* __restrict__ B2,
    const float* __restrict__ bias0, const float* __restrict__ bias1,
    const float* __restrict__ bias2,
    short* __restrict__ o0, short* __restrict__ o1, short* __restrict__ o2,
    float* __restrict__ outf, int N) {
  __shared__ __align__(16) short As[2][4096];
  __shared__ __align__(16) short Bs[2][4096];
  constexpr int nIter = K / 32;
  int z = blockIdx.z;
  const short* Bt = (z == 0) ? B0 : (z == 1) ? B1 : B2;
  const float* bias = (z == 0) ? bias0 : (z == 1) ? bias1 : bias2;
  short* outz = (z == 0) ? o0 : (z == 1) ? o1 : o2;
  int m0 = blockIdx.x * 128, n0 = blockIdx.y * 128;
  int tid = threadIdx.x;
  int lane = tid & 63, w = tid >> 6;
  int q = lane >> 4, r = lane & 15;
  int wm = (w >> 1) * 64, wn = (w & 1) * 64;
  const short* At = A + (size_t)blockIdx.x * nIter * 4096;
  const short* Btl = Bt + (size_t)blockIdx.y * nIter * 4096;
  f32x4 vzero = {0.f, 0.f, 0.f, 0.f};
  f32x4 acc[4][4];
#pragma unroll
  for (int i = 0; i < 4; ++i)
#pragma unroll
    for (int j = 0; j < 4; ++j) acc[i][j] = vzero;

  int c0 = tid * 8, c1 = (tid + 256) * 8;
  // prologue: groups 0,1
#pragma unroll
  for (int g = 0; g < 2; ++g) {
    gld16(At + g * 4096 + c0, &As[g][c0]);
    gld16(At + g * 4096 + c1, &As[g][c1]);
    gld16(Btl + g * 4096 + c0, &Bs[g][c0]);
    gld16(Btl + g * 4096 + c1, &Bs[g][c1]);
  }

  // per-wave LDS fragment bases (element index)
  int abase = (q * 128 + wm + r) * 8;
  int bbase = (q * 128 + wn + r) * 8;

#pragma unroll
  for (int gi = 0; gi < nIter - 1; ++gi) {
    __builtin_amdgcn_s_waitcnt(0x0f74);  // vmcnt(4): group gi landed (mine)
    __builtin_amdgcn_s_barrier();        // everyone's group gi landed
    const int cur = gi & 1;
    bf16x8 af[4], bfr[4];
#pragma unroll
    for (int mt = 0; mt < 4; ++mt)
      af[mt] = *(const bf16x8*)&As[cur][abase + mt * 16 * 8];
#pragma unroll
    for (int nt = 0; nt < 4; ++nt)
      bfr[nt] = *(const bf16x8*)&Bs[cur][bbase + nt * 16 * 8];
#pragma unroll
    for (int mt = 0; mt < 4; ++mt)
#pragma unroll
      for (int nt = 0; nt < 4; ++nt)
        acc[mt][nt] = __builtin_amdgcn_mfma_f32_16x16x32_bf16(bfr[nt], af[mt], acc[mt][nt], 0, 0, 0);
    __builtin_amdgcn_s_waitcnt(0xc07f);  // lgkmcnt(0): my ds_reads done
    __builtin_amdgcn_s_barrier();        // all waves done with buf cur
    if (gi + 2 < nIter) {                // refill buf cur with group gi+2
      size_t kn = (size_t)(gi + 2) * 4096;
      gld16(At + kn + c0, &As[cur][c0]);
      gld16(At + kn + c1, &As[cur][c1]);
      gld16(Btl + kn + c0, &Bs[cur][c0]);
      gld16(Btl + kn + c1, &Bs[cur][c1]);
    }
  }
  // final iteration (group nIter-1, buf (nIter-1)&1)
  {
    __builtin_amdgcn_s_waitcnt(0x0f70);  // vmcnt(0)
    __builtin_amdgcn_s_barrier();
    const int cur = (nIter - 1) & 1;
    bf16x8 af[4], bfr[4];
#pragma unroll
    for (int mt = 0; mt < 4; ++mt)
      af[mt] = *(const bf16x8*)&As[cur][abase + mt * 16 * 8];
#pragma unroll
    for (int nt = 0; nt < 4; ++nt)
      bfr[nt] = *(const bf16x8*)&Bs[cur][bbase + nt * 16 * 8];
#pragma unroll
    for (int mt = 0; mt < 4; ++mt)
#pragma unroll
      for (int nt = 0; nt < 4; ++nt)
        acc[mt][nt] = __builtin_amdgcn_mfma_f32_16x16x32_bf16(bfr[nt], af[mt], acc[mt][nt], 0, 0, 0);
  }

  // epilogue: m = m0+wm+mt*16+r, n = n0+wn+nt*16+q*4+[0..3]
  float4 bias4[4];
#pragma unroll
  for (int nt = 0; nt < 4; ++nt) bias4[nt] = *(const float4*)&bias[n0 + wn + nt * 16 + q * 4];
#pragma unroll
  for (int mt = 0; mt < 4; ++mt) {
    int ml = wm + mt * 16 + r;
    int m = m0 + ml;
    size_t rowoff = (size_t)m * N + n0 + wn + q * 4;
#pragma unroll
    for (int nt = 0; nt < 4; ++nt) {
      f32x4 v = acc[mt][nt];
      v[0] += bias4[nt].x; v[1] += bias4[nt].y; v[2] += bias4[nt].z; v[3] += bias4[nt].w;
      if (EPI == 0) {
        if (z < 2) { v[0] *= v[0]; v[1] *= v[1]; v[2] *= v[2]; v[3] *= v[3]; }
        short4 o; o.x = f2bf(v[0]); o.y = f2bf(v[1]); o.z = f2bf(v[2]); o.w = f2bf(v[3]);
        *(short4*)&outz[rowoff + nt * 16] = o;
      } else if (EPI == 1) {
#pragma unroll
        for (int e = 0; e < 4; ++e) v[e] = fast_gelu(v[e]);
        short4 o; o.x = f2bf(v[0]); o.y = f2bf(v[1]); o.z = f2bf(v[2]); o.w = f2bf(v[3]);
        int n = n0 + wn + nt * 16 + q * 4;
        size_t ti = ((size_t)blockIdx.x * (N >> 5) + (n >> 5)) * 4096 +
                    (size_t)(((n >> 3) & 3) << 10) + (ml << 3) + (n & 7);
        *(short4*)&outz[ti] = o;
      } else {
        float4 cur4 = *(float4*)&outf[rowoff + nt * 16];
        cur4.x += v[0]; cur4.y += v[1]; cur4.z += v[2]; cur4.w += v[3];
        *(float4*)&outf[rowoff + nt * 16] = cur4;
      }
    }
  }
}

// ---------------- attention A1: per (b,h,chunk) S_c = K^T V, z_c = sum k ------
__global__ __launch_bounds__(256) void attn_chunk_kv(
    const short* __restrict__ Kb, const short* __restrict__ Vb,
    float* __restrict__ St, float* __restrict__ Zc) {
  __shared__ short Kt[4][32 * 72];
  __shared__ short Vt[4][32 * 72];
  int wid = threadIdx.x >> 6;
  int blk = blockIdx.x * 4 + wid;
  int c = blk & (NC - 1), bh = blk >> 5;
  int b = bh >> 3, hh = bh & 7;
  int lane = threadIdx.x & 63, q = lane >> 4, r = lane & 15;
  size_t rowbase = ((size_t)(b * GG + c * CS + lane)) * DD + hh * 32;
#pragma unroll
  for (int j = 0; j < 4; ++j) {
    bf16x8 kv = *(const bf16x8*)&Kb[rowbase + j * 8];
    bf16x8 vv = *(const bf16x8*)&Vb[rowbase + j * 8];
#pragma unroll
    for (int e = 0; e < 8; ++e) {
      Kt[wid][(j * 8 + e) * 72 + lane] = kv[e];
      Vt[wid][(j * 8 + e) * 72 + lane] = vv[e];
    }
  }
  __syncthreads();
  f32x4 vzero = {0.f, 0.f, 0.f, 0.f};
  f32x4 acc[2][2];
#pragma unroll
  for (int i = 0; i < 2; ++i)
#pragma unroll
    for (int j = 0; j < 2; ++j) acc[i][j] = vzero;
#pragma unroll
  for (int ks = 0; ks < 2; ++ks) {
    bf16x8 afr[2], bfr[2];
#pragma unroll
    for (int mt = 0; mt < 2; ++mt) afr[mt] = *(const bf16x8*)&Kt[wid][(mt * 16 + r) * 72 + ks * 32 + q * 8];
#pragma unroll
    for (int nt = 0; nt < 2; ++nt) bfr[nt] = *(const bf16x8*)&Vt[wid][(nt * 16 + r) * 72 + ks * 32 + q * 8];
#pragma unroll
    for (int mt = 0; mt < 2; ++mt)
#pragma unroll
      for (int nt = 0; nt < 2; ++nt)
        acc[mt][nt] = __builtin_amdgcn_mfma_f32_16x16x32_bf16(afr[mt], bfr[nt], acc[mt][nt], 0, 0, 0);
  }
  float* stp = St + ((size_t)bh * NC + c) * 1024;
#pragma unroll
  for (int mt = 0; mt < 2; ++mt)
#pragma unroll
    for (int nt = 0; nt < 2; ++nt)
      *(f32x4*)&stp[(nt * 16 + r) * 32 + mt * 16 + q * 4] = acc[mt][nt];  // St[d][f]
  if (lane < 32) {
    float s = 0.f;
#pragma unroll
    for (int j = 0; j < 8; ++j) {
      bf16x8 kr = *(const bf16x8*)&Kt[wid][lane * 72 + j * 8];
#pragma unroll
      for (int e = 0; e < 8; ++e) s += bf2f(kr[e]);
    }
    Zc[((size_t)bh * NC + c) * 32 + lane] = s;
  }
}

// ---------------- attention A2: exclusive prefix over chunks ------------------
__global__ __launch_bounds__(1024) void attn_prefix(float* __restrict__ St, float* __restrict__ Zc) {
  int bh = blockIdx.x, i = threadIdx.x;
  float run = 0.f;
  float* p = St + (size_t)bh * NC * 1024 + i;
#pragma unroll
  for (int c = 0; c < NC; ++c) { float t = p[(size_t)c * 1024]; p[(size_t)c * 1024] = run; run += t; }
  if (i < 32) {
    float rz = 0.f;
    float* pz = Zc + (size_t)bh * NC * 32 + i;
#pragma unroll
    for (int c = 0; c < NC; ++c) { float t = pz[c * 32]; pz[c * 32] = rz; rz += t; }
  }
}

// ---------------- attention B: intra-chunk + apply, h += out ------------------
__global__ __launch_bounds__(256) void attn_intra(
    const short* __restrict__ Qb, const short* __restrict__ Kb,
    const short* __restrict__ Vb, const float* __restrict__ St,
    const float* __restrict__ Zc, float* __restrict__ h) {
  __shared__ short P[4][64 * 72];
  __shared__ short Vt[4][32 * 72];
  __shared__ float den[4][64];
  int wid = threadIdx.x >> 6;
  int blk = blockIdx.x * 4 + wid;
  int c = blk & (NC - 1), bh = blk >> 5;
  int b = bh >> 3, hh = bh & 7;
  int lane = threadIdx.x & 63, q = lane >> 4, r = lane & 15;
  size_t row0 = (size_t)b * GG + c * CS;

  const float* zp = Zc + ((size_t)bh * NC + c) * 32;
  float qz = 0.f;
  {
    size_t qoff = (row0 + lane) * DD + hh * 32;
#pragma unroll
    for (int j = 0; j < 4; ++j) {
      bf16x8 qv = *(const bf16x8*)&Qb[qoff + j * 8];
#pragma unroll
      for (int e = 0; e < 8; ++e) qz += bf2f(qv[e]) * zp[j * 8 + e];
    }
  }
  den[wid][lane] = qz;

  {
    size_t voff = (row0 + lane) * DD + hh * 32;
#pragma unroll
    for (int j = 0; j < 4; ++j) {
      bf16x8 vv = *(const bf16x8*)&Vb[voff + j * 8];
#pragma unroll
      for (int e = 0; e < 8; ++e) Vt[wid][(j * 8 + e) * 72 + lane] = vv[e];
    }
  }

  bf16x8 ak[4], bqf[4];
#pragma unroll
  for (int t4 = 0; t4 < 4; ++t4) {
    ak[t4]  = *(const bf16x8*)&Kb[(row0 + t4 * 16 + r) * DD + hh * 32 + q * 8];
    bqf[t4] = *(const bf16x8*)&Qb[(row0 + t4 * 16 + r) * DD + hh * 32 + q * 8];
  }
  f32x4 vzero = {0.f, 0.f, 0.f, 0.f};
  f32x4 pacc[4][4];
#pragma unroll
  for (int mt = 0; mt < 4; ++mt)
#pragma unroll
    for (int nt = 0; nt < 4; ++nt)
      pacc[mt][nt] = __builtin_amdgcn_mfma_f32_16x16x32_bf16(ak[mt], bqf[nt], vzero, 0, 0, 0);

  float rs[4] = {0.f, 0.f, 0.f, 0.f};
#pragma unroll
  for (int nt = 0; nt < 4; ++nt) {
    int t = nt * 16 + r;
#pragma unroll
    for (int mt = 0; mt < 4; ++mt) {
      short4 pk;
#pragma unroll
      for (int rr = 0; rr < 4; ++rr) {
        int s = mt * 16 + q * 4 + rr;
        float pv = (s <= t) ? pacc[mt][nt][rr] : 0.f;
        rs[nt] += pv;
        ((short*)&pk)[rr] = f2bf(pv);
      }
      *(short4*)&P[wid][t * 72 + mt * 16 + q * 4] = pk;
    }
  }
#pragma unroll
  for (int nt = 0; nt < 4; ++nt) {
    rs[nt] += __shfl_xor(rs[nt], 16);
    rs[nt] += __shfl_xor(rs[nt], 32);
  }
  __syncthreads();
  if (lane < 16) {
#pragma unroll
    for (int nt = 0; nt < 4; ++nt) den[wid][nt * 16 + lane] += rs[nt];
  }
  __syncthreads();

  f32x4 oacc[4][2];
#pragma unroll
  for (int mt = 0; mt < 4; ++mt)
#pragma unroll
    for (int nt2 = 0; nt2 < 2; ++nt2) oacc[mt][nt2] = vzero;
  const float* stp = St + ((size_t)bh * NC + c) * 1024;
#pragma unroll
  for (int nt2 = 0; nt2 < 2; ++nt2) {
    float4 s0 = *(const float4*)&stp[(nt2 * 16 + r) * 32 + q * 8];
    float4 s1 = *(const float4*)&stp[(nt2 * 16 + r) * 32 + q * 8 + 4];
    bf16x8 bs;
    bs[0] = f2bf(s0.x); bs[1] = f2bf(s0.y); bs[2] = f2bf(s0.z); bs[3] = f2bf(s0.w);
    bs[4] = f2bf(s1.x); bs[5] = f2bf(s1.y); bs[6] = f2bf(s1.z); bs[7] = f2bf(s1.w);
#pragma unroll
    for (int mt = 0; mt < 4; ++mt)
      oacc[mt][nt2] = __builtin_amdgcn_mfma_f32_16x16x32_bf16(bqf[mt], bs, oacc[mt][nt2], 0, 0, 0);
  }
#pragma unroll
  for (int ks = 0; ks < 2; ++ks) {
    bf16x8 ap[4];
#pragma unroll
    for (int mt = 0; mt < 4; ++mt)
      ap[mt] = *(const bf16x8*)&P[wid][(mt * 16 + r) * 72 + ks * 32 + q * 8];
#pragma unroll
    for (int nt2 = 0; nt2 < 2; ++nt2) {
      bf16x8 bv_ = *(const bf16x8*)&Vt[wid][(nt2 * 16 + r) * 72 + ks * 32 + q * 8];
#pragma unroll
      for (int mt = 0; mt < 4; ++mt)
        oacc[mt][nt2] = __builtin_amdgcn_mfma_f32_16x16x32_bf16(ap[mt], bv_, oacc[mt][nt2], 0, 0, 0);
    }
  }

#pragma unroll
  for (int mt = 0; mt < 4; ++mt) {
#pragma unroll
    for (int rr = 0; rr < 4; ++rr) {
      int t = mt * 16 + q * 4 + rr;
      float inv = 1.0f / (den[wid][t] + 1e-16f);
#pragma unroll
      for (int nt2 = 0; nt2 < 2; ++nt2) {
        int d = nt2 * 16 + r;
        size_t off = (row0 + t) * DD + hh * 32 + d;
        h[off] += oacc[mt][nt2][rr] * inv;
      }
    }
  }
}

// ---------------- final projection -------------------------------------------
__global__ __launch_bounds__(256) void out_proj(
    const float* __restrict__ h, const float* __restrict__ Wout,
    const float* __restrict__ bout, float* __restrict__ out) {
  int row = blockIdx.x * 4 + (threadIdx.x >> 6);
  int lane = threadIdx.x & 63;
  float4 a = *(const float4*)&h[(size_t)row * DD + lane * 4];
  float4 w = *(const float4*)&Wout[lane * 4];
  float s = a.x * w.x + a.y * w.y + a.z * w.z + a.w * w.w;
#pragma unroll
  for (int o = 1; o < 64; o <<= 1) s += __shfl_xor(s, o);
  if (lane == 0) out[row] = s + bout[0];
}

extern "C" void kernel_launch(void* const* d_in, const int* in_sizes, int n_in,
                              void* d_out, int out_size, void* d_ws, size_t ws_size,
                              hipStream_t stream) {
  const float* x    = (const float*)d_in[0];
  const float* ge   = (const float*)d_in[1];
  const float* invf = (const float*)d_in[2];
  const float* Wq   = (const float*)d_in[3];
  const float* bq   = (const float*)d_in[4];
  const float* Wk   = (const float*)d_in[5];
  const float* bk   = (const float*)d_in[6];
  const float* Wv   = (const float*)d_in[7];
  const float* bv   = (const float*)d_in[8];
  const float* ln1g = (const float*)d_in[9];
  const float* ln1b = (const float*)d_in[10];
  const float* ln2g = (const float*)d_in[11];
  const float* ln2b = (const float*)d_in[12];
  const float* WU   = (const float*)d_in[13];
  const float* bU   = (const float*)d_in[14];
  const float* WV   = (const float*)d_in[15];
  const float* bV   = (const float*)d_in[16];
  const float* Wout = (const float*)d_in[17];
  const float* bout = (const float*)d_in[18];
  float* out = (float*)d_out;

  char* ws = (char*)d_ws;
  float* h   = (float*)(ws + 0);            // 33.5 MB
  short* hn  = (short*)(ws + 33554432);     // 16.8 MB (tiled)
  char*  R   = ws + 50331648;               // shared region
  short* qb  = (short*)(R + 0);
  short* kb  = (short*)(R + 16777216);
  short* vb  = (short*)(R + 33554432);
  float* St  = (float*)(R + 50331648);
  float* Zc  = (float*)(R + 67108864);
  short* mid = (short*)(R + 0);             // FFN phase (tiled, overlaps q/k/v)
  char*  WT  = R + 67633152;
  short* TQ  = (short*)(WT + 0);
  short* TK  = (short*)(WT + 524288);
  short* TVq = (short*)(WT + 1048576);
  short* TU  = (short*)(WT + 1572864);
  short* TVd = (short*)(WT + 3670016);

  prep_weights<<<dim3(1024, 4, 5), 256, 0, stream>>>(Wq, Wk, Wv, WU, WV, TQ, TK, TVq, TU, TVd);
  embed_kernel<<<NROWS / 4, 256, 0, stream>>>(x, ge, invf, h);

  for (int l = 0; l < 4; ++l) {
    ln_tiled<<<NROWS / 32, 256, 0, stream>>>(h, ln1g + l * 256, ln1b + l * 256, hn);
    gemm_t<256, 0><<<dim3(256, 2, 3), 256, 0, stream>>>(
        hn, TQ + l * 65536, TK + l * 65536, TVq + l * 65536,
        bq + l * 256, bk + l * 256, bv + l * 256,
        qb, kb, vb, nullptr, 256);
    attn_chunk_kv<<<1024, 256, 0, stream>>>(kb, vb, St, Zc);
    attn_prefix<<<128, 1024, 0, stream>>>(St, Zc);
    attn_intra<<<1024, 256, 0, stream>>>(qb, kb, vb, St, Zc, h);
    ln_tiled<<<NROWS / 32, 256, 0, stream>>>(h, ln2g + l * 256, ln2b + l * 256, hn);
    gemm_t<256, 1><<<dim3(256, 8, 1), 256, 0, stream>>>(
        hn, TU + l * 262144, nullptr, nullptr,
        bU + l * 1024, nullptr, nullptr,
        mid, nullptr, nullptr, nullptr, 1024);
    gemm_t<1024, 2><<<dim3(256, 2, 1), 256, 0, stream>>>(
        mid, TVd + l * 262144, nullptr, nullptr,
        bV + l * 256, nullptr, nullptr,
        nullptr, nullptr, nullptr, h, 256);
  }
  out_proj<<<NROWS / 4, 256, 0, stream>>>(h, Wout, bout, out);
}

// Round 9
// 762.509 us; speedup vs baseline: 1.5306x; 1.0365x over previous
//
#include <hip/hip_runtime.h>
#include <math.h>

// ExpressionPerformer: B=16,G=2048,D=256,H=8,dh=32,FFN=1024,L=4
// Round-9:
//  - gemm: unrolled (R8) + 3-buffer rolling pipeline (R7) combined: 2-iter
//    prefetch slack (~1000cyc) >= HBM latency (~900cyc), constant waitcnts.
//  - q/k/v stored HEAD-MAJOR [head][32768][32] via LDS-transpose epilogue:
//    kills QKV 8B@512B-stride scatter writes AND attention scatter reads
//    (both now 64B/lane contiguous). Same fix class as R7's +17% win.
//  - FFN-down h+= staged through LDS: coalesced 128B fp32 RMW (was 1KB stride).

#define GG 2048
#define DD 256
#define NROWS 32768
#define NC 32
#define CS 64

typedef __attribute__((ext_vector_type(8))) short bf16x8;
typedef __attribute__((ext_vector_type(4))) float f32x4;

__device__ __forceinline__ short f2bf(float f) {
  union { float f; unsigned u; } v; v.f = f;
  unsigned r = v.u + 0x7FFFu + ((v.u >> 16) & 1u);
  return (short)(r >> 16);
}
__device__ __forceinline__ float bf2f(short s) {
  union { unsigned u; float f; } v; v.u = ((unsigned)(unsigned short)s) << 16;
  return v.f;
}
__device__ __forceinline__ void gld16(const short* g, short* l) {
  __builtin_amdgcn_global_load_lds(
      (const __attribute__((address_space(1))) void*)g,
      (__attribute__((address_space(3))) void*)l, 16, 0, 0);
}
__device__ __forceinline__ float fast_gelu(float x) {
  float y = 1.595769122f * (x + 0.044715f * x * x * x);
  return x / (1.0f + __expf(-y));
}

// ---------------- embed ------------------------------------------------------
__global__ __launch_bounds__(256) void embed_kernel(
    const float* __restrict__ x, const float* __restrict__ ge,
    const float* __restrict__ invf, float* __restrict__ h) {
  int bg = blockIdx.x * 4 + (threadIdx.x >> 6);
  int g = bg & (GG - 1);
  int lane = threadIdx.x & 63;
  float xv = x[bg];
  int d = lane * 4;
  float4 e;
  if (lane < 32) {
    float4 f = *(const float4*)&invf[d];
    e.x = sinf(xv * f.x); e.y = sinf(xv * f.y);
    e.z = sinf(xv * f.z); e.w = sinf(xv * f.w);
  } else {
    float4 f = *(const float4*)&invf[d - 128];
    e.x = cosf(xv * f.x); e.y = cosf(xv * f.y);
    e.z = cosf(xv * f.z); e.w = cosf(xv * f.w);
  }
  if (xv == -10.0f) { e.x = 0.f; e.y = 0.f; e.z = 0.f; e.w = 0.f; }
  float4 gv = *(const float4*)&ge[(size_t)g * DD + d];
  float4 o; o.x = gv.x + e.x; o.y = gv.y + e.y; o.z = gv.z + e.z; o.w = gv.w + e.w;
  *(float4*)&h[(size_t)bg * DD + d] = o;
}

// ---------------- layernorm -> TILED bf16 ------------------------------------
__global__ __launch_bounds__(256) void ln_tiled(
    const float* __restrict__ h, const float* __restrict__ gamma,
    const float* __restrict__ beta, short* __restrict__ outT) {
  __shared__ float mean_s[32], rstd_s[32];
  __shared__ float gls[256], bls[256];
  int r0 = blockIdx.x * 32;
  int tid = threadIdx.x;
  gls[tid] = gamma[tid]; bls[tid] = beta[tid];
  {
    int row = tid >> 3, seg = tid & 7;
    const float4* hp = (const float4*)(h + (size_t)(r0 + row) * DD + seg * 32);
    float s = 0.f, s2 = 0.f;
#pragma unroll
    for (int i = 0; i < 8; ++i) {
      float4 v = hp[i];
      s += v.x + v.y + v.z + v.w;
      s2 += v.x * v.x + v.y * v.y + v.z * v.z + v.w * v.w;
    }
    s += __shfl_xor(s, 1); s += __shfl_xor(s, 2); s += __shfl_xor(s, 4);
    s2 += __shfl_xor(s2, 1); s2 += __shfl_xor(s2, 2); s2 += __shfl_xor(s2, 4);
    if (seg == 0) {
      float mn = s * (1.0f / 256.0f);
      mean_s[row] = mn;
      rstd_s[row] = rsqrtf(s2 * (1.0f / 256.0f) - mn * mn + 1e-5f);
    }
  }
  __syncthreads();
  int row = tid & 31, kc8 = (tid >> 5) & 3, half = tid >> 7;
  float mn = mean_s[row], rs = rstd_s[row];
  size_t hrow = (size_t)(r0 + row) * DD;
  int trow = (r0 & 127) + row;
  short* tb = outT + (size_t)(r0 >> 7) * 8 * 4096 + (kc8 * 128 + trow) * 8;
#pragma unroll
  for (int j = 0; j < 4; ++j) {
    int kb = half * 4 + j;
    int k0 = kb * 32 + kc8 * 8;
    float4 x0 = *(const float4*)&h[hrow + k0];
    float4 x1 = *(const float4*)&h[hrow + k0 + 4];
    float4 g0 = *(const float4*)&gls[k0], g1 = *(const float4*)&gls[k0 + 4];
    float4 b0 = *(const float4*)&bls[k0], b1 = *(const float4*)&bls[k0 + 4];
    bf16x8 aw;
    aw[0] = f2bf((x0.x - mn) * rs * g0.x + b0.x);
    aw[1] = f2bf((x0.y - mn) * rs * g0.y + b0.y);
    aw[2] = f2bf((x0.z - mn) * rs * g0.z + b0.z);
    aw[3] = f2bf((x0.w - mn) * rs * g0.w + b0.w);
    aw[4] = f2bf((x1.x - mn) * rs * g1.x + b1.x);
    aw[5] = f2bf((x1.y - mn) * rs * g1.y + b1.y);
    aw[6] = f2bf((x1.z - mn) * rs * g1.z + b1.z);
    aw[7] = f2bf((x1.w - mn) * rs * g1.w + b1.w);
    *(bf16x8*)&tb[(size_t)kb * 4096] = aw;
  }
}

// ---------------- weight convert+transpose -> TILED --------------------------
__global__ __launch_bounds__(256) void prep_weights(
    const float* __restrict__ Wq, const float* __restrict__ Wk,
    const float* __restrict__ Wv, const float* __restrict__ WU,
    const float* __restrict__ WV,
    short* __restrict__ TQ, short* __restrict__ TK, short* __restrict__ TV,
    short* __restrict__ TU, short* __restrict__ TVd) {
  int zz = blockIdx.z, l = blockIdx.y;
  const float* src; short* dst; int Kd, Nd;
  if (zz == 0) { src = Wq; dst = TQ; Kd = 256; Nd = 256; }
  else if (zz == 1) { src = Wk; dst = TK; Kd = 256; Nd = 256; }
  else if (zz == 2) { src = Wv; dst = TV; Kd = 256; Nd = 256; }
  else if (zz == 3) { src = WU; dst = TU; Kd = 256; Nd = 1024; }
  else { src = WV; dst = TVd; Kd = 1024; Nd = 256; }
  int tot = Kd * Nd;
  int e = blockIdx.x * 256 + threadIdx.x;
  if (e >= tot) return;
  int t = e >> 12;
  int cslot = (e >> 3) & 511;
  int elem = e & 7;
  int kc8 = cslot >> 7, rn = cslot & 127;
  int nKb = Kd >> 5;
  int nt = t / nKb, kb = t - nt * nKb;
  int n = nt * 128 + rn, k = kb * 32 + kc8 * 8 + elem;
  dst[(size_t)l * tot + e] = f2bf(src[(size_t)l * tot + (size_t)k * Nd + n]);
}

// ---------------- bf16 MFMA GEMM (tiled operands, compile-time K) -------------
// 3-buffer rolling pipeline, fully unrolled. EPI 0: square(z<2), HEAD-MAJOR
// bf16 out via LDS transpose; 1: gelu, tiled bf16 out; 2: h += acc+bias via LDS.
template <int K, int EPI>
__global__ __launch_bounds__(256) void gemm_t(
    const short* __restrict__ A, const short* __restrict__ B0,
    const short* __restrict__ B1, const short* __restrict__ B2,
    const float* __restrict__ bias0, const float* __restrict__ bias1,
    const float* __restrict__ bias2,
    short* __restrict__ o0, short* __restrict__ o1, short* __restrict__ o2,
    float* __restrict__ outf, int N) {
  __shared__ __align__(16) short L[24576];  // 48KB: As g @ g*4096, Bs g @ 12288+g*4096
  constexpr int nIter = K / 32;
  int z = blockIdx.z;
  const short* Bt = (z == 0) ? B0 : (z == 1) ? B1 : B2;
  const float* bias = (z == 0) ? bias0 : (z == 1) ? bias1 : bias2;
  short* outz = (z == 0) ? o0 : (z == 1) ? o1 : o2;
  int m0 = blockIdx.x * 128, n0 = blockIdx.y * 128;
  int tid = threadIdx.x;
  int lane = tid & 63, w = tid >> 6;
  int q = lane >> 4, r = lane & 15;
  int wm = (w >> 1) * 64, wn = (w & 1) * 64;
  const short* At = A + (size_t)blockIdx.x * nIter * 4096;
  const short* Btl = Bt + (size_t)blockIdx.y * nIter * 4096;
  f32x4 vzero = {0.f, 0.f, 0.f, 0.f};
  f32x4 acc[4][4];
#pragma unroll
  for (int i = 0; i < 4; ++i)
#pragma unroll
    for (int j = 0; j < 4; ++j) acc[i][j] = vzero;

  int c0 = tid * 8, c1 = (tid + 256) * 8;
  // prologue: groups 0,1,2
#pragma unroll
  for (int g = 0; g < 3; ++g) {
    gld16(At + g * 4096 + c0, &L[g * 4096 + c0]);
    gld16(At + g * 4096 + c1, &L[g * 4096 + c1]);
    gld16(Btl + g * 4096 + c0, &L[12288 + g * 4096 + c0]);
    gld16(Btl + g * 4096 + c1, &L[12288 + g * 4096 + c1]);
  }

  int abase = (q * 128 + wm + r) * 8;
  int bbase = (q * 128 + wn + r) * 8;

#pragma unroll
  for (int gi = 0; gi < nIter; ++gi) {
    const int rem = nIter - 1 - gi;  // groups still needed after this one
    if (rem >= 2)      __builtin_amdgcn_s_waitcnt(0x0f78);  // vmcnt(8)
    else if (rem == 1) __builtin_amdgcn_s_waitcnt(0x0f74);  // vmcnt(4)
    else               __builtin_amdgcn_s_waitcnt(0x0f70);  // vmcnt(0)
    __builtin_amdgcn_s_barrier();
    const int cur = gi % 3;
    const short* Asc = &L[cur * 4096];
    const short* Bsc = &L[12288 + cur * 4096];
    bf16x8 af[4], bfr[4];
#pragma unroll
    for (int mt = 0; mt < 4; ++mt)
      af[mt] = *(const bf16x8*)&Asc[abase + mt * 16 * 8];
#pragma unroll
    for (int nt = 0; nt < 4; ++nt)
      bfr[nt] = *(const bf16x8*)&Bsc[bbase + nt * 16 * 8];
#pragma unroll
    for (int mt = 0; mt < 4; ++mt)
#pragma unroll
      for (int nt = 0; nt < 4; ++nt)
        acc[mt][nt] = __builtin_amdgcn_mfma_f32_16x16x32_bf16(bfr[nt], af[mt], acc[mt][nt], 0, 0, 0);
    __builtin_amdgcn_s_waitcnt(0xc07f);  // lgkmcnt(0)
    __builtin_amdgcn_s_barrier();
    if (gi + 3 < nIter) {
      size_t kn = (size_t)(gi + 3) * 4096;
      gld16(At + kn + c0, &L[cur * 4096 + c0]);
      gld16(At + kn + c1, &L[cur * 4096 + c1]);
      gld16(Btl + kn + c0, &L[12288 + cur * 4096 + c0]);
      gld16(Btl + kn + c1, &L[12288 + cur * 4096 + c1]);
    }
  }

  float4 bias4[4];
#pragma unroll
  for (int nt = 0; nt < 4; ++nt) bias4[nt] = *(const float4*)&bias[n0 + wn + nt * 16 + q * 4];

  if (EPI == 0) {
    // stage tile to LDS [128][132] (pad: 2-way-free banks), then write head-major
    short* T = L;
#pragma unroll
    for (int mt = 0; mt < 4; ++mt) {
      int ml = wm + mt * 16 + r;
#pragma unroll
      for (int nt = 0; nt < 4; ++nt) {
        f32x4 v = acc[mt][nt];
        v[0] += bias4[nt].x; v[1] += bias4[nt].y; v[2] += bias4[nt].z; v[3] += bias4[nt].w;
        if (z < 2) { v[0] *= v[0]; v[1] *= v[1]; v[2] *= v[2]; v[3] *= v[3]; }
        short4 pk; pk.x = f2bf(v[0]); pk.y = f2bf(v[1]); pk.z = f2bf(v[2]); pk.w = f2bf(v[3]);
        *(short4*)&T[ml * 132 + wn + nt * 16 + q * 4] = pk;
      }
    }
    __syncthreads();
#pragma unroll
    for (int t2 = 0; t2 < 2; ++t2) {
      int task = tid + t2 * 256;
      int row = task & 127, hl = task >> 7;
      size_t obase = ((size_t)((n0 >> 5) + hl) * NROWS + m0 + row) * 32;
#pragma unroll
      for (int j = 0; j < 4; ++j)
        *(bf16x8*)&outz[obase + j * 8] = *(const bf16x8*)&T[row * 132 + hl * 32 + j * 8];
    }
  } else if (EPI == 1) {
#pragma unroll
    for (int mt = 0; mt < 4; ++mt) {
      int ml = wm + mt * 16 + r;
#pragma unroll
      for (int nt = 0; nt < 4; ++nt) {
        f32x4 v = acc[mt][nt];
        v[0] += bias4[nt].x; v[1] += bias4[nt].y; v[2] += bias4[nt].z; v[3] += bias4[nt].w;
#pragma unroll
        for (int e = 0; e < 4; ++e) v[e] = fast_gelu(v[e]);
        short4 o; o.x = f2bf(v[0]); o.y = f2bf(v[1]); o.z = f2bf(v[2]); o.w = f2bf(v[3]);
        int n = n0 + wn + nt * 16 + q * 4;
        size_t ti = ((size_t)blockIdx.x * (N >> 5) + (n >> 5)) * 4096 +
                    (size_t)(((n >> 3) & 3) << 10) + (ml << 3) + (n & 7);
        *(short4*)&outz[ti] = o;
      }
    }
  } else {
    // h += acc + bias, staged via LDS [128][68] f32, two 64-n rounds
    float* TF = (float*)L;
#pragma unroll
    for (int half = 0; half < 2; ++half) {
      __syncthreads();
      if ((w & 1) == half) {
#pragma unroll
        for (int mt = 0; mt < 4; ++mt) {
          int ml = wm + mt * 16 + r;
#pragma unroll
          for (int nt = 0; nt < 4; ++nt) {
            f32x4 v = acc[mt][nt];
            v[0] += bias4[nt].x; v[1] += bias4[nt].y; v[2] += bias4[nt].z; v[3] += bias4[nt].w;
            *(f32x4*)&TF[ml * 68 + nt * 16 + q * 4] = v;
          }
        }
      }
      __syncthreads();
      int row = tid >> 1, col = (tid & 1) * 32;
      size_t hoff = (size_t)(m0 + row) * N + n0 + half * 64 + col;
#pragma unroll
      for (int j = 0; j < 8; ++j) {
        float4 add = *(const float4*)&TF[row * 68 + col + j * 4];
        float4 cur4 = *(float4*)&outf[hoff + j * 4];
        cur4.x += add.x; cur4.y += add.y; cur4.z += add.z; cur4.w += add.w;
        *(float4*)&outf[hoff + j * 4] = cur4;
      }
    }
  }
}

// ---------------- attention A1: per (b,h,chunk) S_c = K^T V, z_c = sum k ------
// q/k/v head-major: [head][32768][32]
__global__ __launch_bounds__(256) void attn_chunk_kv(
    const short* __restrict__ Kb, const short* __restrict__ Vb,
    float* __restrict__ St, float* __restrict__ Zc) {
  __shared__ short Kt[4][32 * 72];
  __shared__ short Vt[4][32 * 72];
  int wid = threadIdx.x >> 6;
  int blk = blockIdx.x * 4 + wid;
  int c = blk & (NC - 1), bh = blk >> 5;
  int b = bh >> 3, hh = bh & 7;
  int lane = threadIdx.x & 63, q = lane >> 4, r = lane & 15;
  size_t rowbase = ((size_t)hh * NROWS + b * GG + c * CS + lane) * 32;
#pragma unroll
  for (int j = 0; j < 4; ++j) {
    bf16x8 kv = *(const bf16x8*)&Kb[rowbase + j * 8];
    bf16x8 vv = *(const bf16x8*)&Vb[rowbase + j * 8];
#pragma unroll
    for (int e = 0; e < 8; ++e) {
      Kt[wid][(j * 8 + e) * 72 + lane] = kv[e];
      Vt[wid][(j * 8 + e) * 72 + lane] = vv[e];
    }
  }
  __syncthreads();
  f32x4 vzero = {0.f, 0.f, 0.f, 0.f};
  f32x4 acc[2][2];
#pragma unroll
  for (int i = 0; i < 2; ++i)
#pragma unroll
    for (int j = 0; j < 2; ++j) acc[i][j] = vzero;
#pragma unroll
  for (int ks = 0; ks < 2; ++ks) {
    bf16x8 afr[2], bfr[2];
#pragma unroll
    for (int mt = 0; mt < 2; ++mt) afr[mt] = *(const bf16x8*)&Kt[wid][(mt * 16 + r) * 72 + ks * 32 + q * 8];
#pragma unroll
    for (int nt = 0; nt < 2; ++nt) bfr[nt] = *(const bf16x8*)&Vt[wid][(nt * 16 + r) * 72 + ks * 32 + q * 8];
#pragma unroll
    for (int mt = 0; mt < 2; ++mt)
#pragma unroll
      for (int nt = 0; nt < 2; ++nt)
        acc[mt][nt] = __builtin_amdgcn_mfma_f32_16x16x32_bf16(afr[mt], bfr[nt], acc[mt][nt], 0, 0, 0);
  }
  float* stp = St + ((size_t)bh * NC + c) * 1024;
#pragma unroll
  for (int mt = 0; mt < 2; ++mt)
#pragma unroll
    for (int nt = 0; nt < 2; ++nt)
      *(f32x4*)&stp[(nt * 16 + r) * 32 + mt * 16 + q * 4] = acc[mt][nt];  // St[d][f]
  if (lane < 32) {
    float s = 0.f;
#pragma unroll
    for (int j = 0; j < 8; ++j) {
      bf16x8 kr = *(const bf16x8*)&Kt[wid][lane * 72 + j * 8];
#pragma unroll
      for (int e = 0; e < 8; ++e) s += bf2f(kr[e]);
    }
    Zc[((size_t)bh * NC + c) * 32 + lane] = s;
  }
}

// ---------------- attention A2: exclusive prefix over chunks ------------------
__global__ __launch_bounds__(1024) void attn_prefix(float* __restrict__ St, float* __restrict__ Zc) {
  int bh = blockIdx.x, i = threadIdx.x;
  float run = 0.f;
  float* p = St + (size_t)bh * NC * 1024 + i;
#pragma unroll
  for (int c = 0; c < NC; ++c) { float t = p[(size_t)c * 1024]; p[(size_t)c * 1024] = run; run += t; }
  if (i < 32) {
    float rz = 0.f;
    float* pz = Zc + (size_t)bh * NC * 32 + i;
#pragma unroll
    for (int c = 0; c < NC; ++c) { float t = pz[c * 32]; pz[c * 32] = rz; rz += t; }
  }
}

// ---------------- attention B: intra-chunk + apply, h += out ------------------
__global__ __launch_bounds__(256) void attn_intra(
    const short* __restrict__ Qb, const short* __restrict__ Kb,
    const short* __restrict__ Vb, const float* __restrict__ St,
    const float* __restrict__ Zc, float* __restrict__ h) {
  __shared__ short P[4][64 * 72];
  __shared__ short Vt[4][32 * 72];
  __shared__ float den[4][64];
  int wid = threadIdx.x >> 6;
  int blk = blockIdx.x * 4 + wid;
  int c = blk & (NC - 1), bh = blk >> 5;
  int b = bh >> 3, hh = bh & 7;
  int lane = threadIdx.x & 63, q = lane >> 4, r = lane & 15;
  size_t hrow0 = (size_t)b * GG + c * CS;                 // rows in h (row-major)
  size_t qrow0 = (size_t)hh * NROWS + b * GG + c * CS;    // rows in head-major qkv

  const float* zp = Zc + ((size_t)bh * NC + c) * 32;
  float qz = 0.f;
  {
    size_t qoff = (qrow0 + lane) * 32;
#pragma unroll
    for (int j = 0; j < 4; ++j) {
      bf16x8 qv = *(const bf16x8*)&Qb[qoff + j * 8];
#pragma unroll
      for (int e = 0; e < 8; ++e) qz += bf2f(qv[e]) * zp[j * 8 + e];
    }
  }
  den[wid][lane] = qz;

  {
    size_t voff = (qrow0 + lane) * 32;
#pragma unroll
    for (int j = 0; j < 4; ++j) {
      bf16x8 vv = *(const bf16x8*)&Vb[voff + j * 8];
#pragma unroll
      for (int e = 0; e < 8; ++e) Vt[wid][(j * 8 + e) * 72 + lane] = vv[e];
    }
  }

  bf16x8 ak[4], bqf[4];
#pragma unroll
  for (int t4 = 0; t4 < 4; ++t4) {
    ak[t4]  = *(const bf16x8*)&Kb[(qrow0 + t4 * 16 + r) * 32 + q * 8];
    bqf[t4] = *(const bf16x8*)&Qb[(qrow0 + t4 * 16 + r) * 32 + q * 8];
  }
  f32x4 vzero = {0.f, 0.f, 0.f, 0.f};
  f32x4 pacc[4][4];
#pragma unroll
  for (int mt = 0; mt < 4; ++mt)
#pragma unroll
    for (int nt = 0; nt < 4; ++nt)
      pacc[mt][nt] = __builtin_amdgcn_mfma_f32_16x16x32_bf16(ak[mt], bqf[nt], vzero, 0, 0, 0);

  float rs[4] = {0.f, 0.f, 0.f, 0.f};
#pragma unroll
  for (int nt = 0; nt < 4; ++nt) {
    int t = nt * 16 + r;
#pragma unroll
    for (int mt = 0; mt < 4; ++mt) {
      short4 pk;
#pragma unroll
      for (int rr = 0; rr < 4; ++rr) {
        int s = mt * 16 + q * 4 + rr;
        float pv = (s <= t) ? pacc[mt][nt][rr] : 0.f;
        rs[nt] += pv;
        ((short*)&pk)[rr] = f2bf(pv);
      }
      *(short4*)&P[wid][t * 72 + mt * 16 + q * 4] = pk;
    }
  }
#pragma unroll
  for (int nt = 0; nt < 4; ++nt) {
    rs[nt] += __shfl_xor(rs[nt], 16);
    rs[nt] += __shfl_xor(rs[nt], 32);
  }
  __syncthreads();
  if (lane < 16) {
#pragma unroll
    for (int nt = 0; nt < 4; ++nt) den[wid][nt * 16 + lane] += rs[nt];
  }
  __syncthreads();

  f32x4 oacc[4][2];
#pragma unroll
  for (int mt = 0; mt < 4; ++mt)
#pragma unroll
    for (int nt2 = 0; nt2 < 2; ++nt2) oacc[mt][nt2] = vzero;
  const float* stp = St + ((size_t)bh * NC + c) * 1024;
#pragma unroll
  for (int nt2 = 0; nt2 < 2; ++nt2) {
    float4 s0 = *(const float4*)&stp[(nt2 * 16 + r) * 32 + q * 8];
    float4 s1 = *(const float4*)&stp[(nt2 * 16 + r) * 32 + q * 8 + 4];
    bf16x8 bs;
    bs[0] = f2bf(s0.x); bs[1] = f2bf(s0.y); bs[2] = f2bf(s0.z); bs[3] = f2bf(s0.w);
    bs[4] = f2bf(s1.x); bs[5] = f2bf(s1.y); bs[6] = f2bf(s1.z); bs[7] = f2bf(s1.w);
#pragma unroll
    for (int mt = 0; mt < 4; ++mt)
      oacc[mt][nt2] = __builtin_amdgcn_mfma_f32_16x16x32_bf16(bqf[mt], bs, oacc[mt][nt2], 0, 0, 0);
  }
#pragma unroll
  for (int ks = 0; ks < 2; ++ks) {
    bf16x8 ap[4];
#pragma unroll
    for (int mt = 0; mt < 4; ++mt)
      ap[mt] = *(const bf16x8*)&P[wid][(mt * 16 + r) * 72 + ks * 32 + q * 8];
#pragma unroll
    for (int nt2 = 0; nt2 < 2; ++nt2) {
      bf16x8 bv_ = *(const bf16x8*)&Vt[wid][(nt2 * 16 + r) * 72 + ks * 32 + q * 8];
#pragma unroll
      for (int mt = 0; mt < 4; ++mt)
        oacc[mt][nt2] = __builtin_amdgcn_mfma_f32_16x16x32_bf16(ap[mt], bv_, oacc[mt][nt2], 0, 0, 0);
    }
  }

#pragma unroll
  for (int mt = 0; mt < 4; ++mt) {
#pragma unroll
    for (int rr = 0; rr < 4; ++rr) {
      int t = mt * 16 + q * 4 + rr;
      float inv = 1.0f / (den[wid][t] + 1e-16f);
#pragma unroll
      for (int nt2 = 0; nt2 < 2; ++nt2) {
        int d = nt2 * 16 + r;
        size_t off = (hrow0 + t) * DD + hh * 32 + d;
        h[off] += oacc[mt][nt2][rr] * inv;
      }
    }
  }
}

// ---------------- final projection -------------------------------------------
__global__ __launch_bounds__(256) void out_proj(
    const float* __restrict__ h, const float* __restrict__ Wout,
    const float* __restrict__ bout, float* __restrict__ out) {
  int row = blockIdx.x * 4 + (threadIdx.x >> 6);
  int lane = threadIdx.x & 63;
  float4 a = *(const float4*)&h[(size_t)row * DD + lane * 4];
  float4 w = *(const float4*)&Wout[lane * 4];
  float s = a.x * w.x + a.y * w.y + a.z * w.z + a.w * w.w;
#pragma unroll
  for (int o = 1; o < 64; o <<= 1) s += __shfl_xor(s, o);
  if (lane == 0) out[row] = s + bout[0];
}

extern "C" void kernel_launch(void* const* d_in, const int* in_sizes, int n_in,
                              void* d_out, int out_size, void* d_ws, size_t ws_size,
                              hipStream_t stream) {
  const float* x    = (const float*)d_in[0];
  const float* ge   = (const float*)d_in[1];
  const float* invf = (const float*)d_in[2];
  const float* Wq   = (const float*)d_in[3];
  const float* bq   = (const float*)d_in[4];
  const float* Wk   = (const float*)d_in[5];
  const float* bk   = (const float*)d_in[6];
  const float* Wv   = (const float*)d_in[7];
  const float* bv   = (const float*)d_in[8];
  const float* ln1g = (const float*)d_in[9];
  const float* ln1b = (const float*)d_in[10];
  const float* ln2g = (const float*)d_in[11];
  const float* ln2b = (const float*)d_in[12];
  const float* WU   = (const float*)d_in[13];
  const float* bU   = (const float*)d_in[14];
  const float* WV   = (const float*)d_in[15];
  const float* bV   = (const float*)d_in[16];
  const float* Wout = (const float*)d_in[17];
  const float* bout = (const float*)d_in[18];
  float* out = (float*)d_out;

  char* ws = (char*)d_ws;
  float* h   = (float*)(ws + 0);            // 33.5 MB
  short* hn  = (short*)(ws + 33554432);     // 16.8 MB (tiled)
  char*  R   = ws + 50331648;               // shared region
  short* qb  = (short*)(R + 0);             // head-major [8][32768][32]
  short* kb  = (short*)(R + 16777216);
  short* vb  = (short*)(R + 33554432);
  float* St  = (float*)(R + 50331648);
  float* Zc  = (float*)(R + 67108864);
  short* mid = (short*)(R + 0);             // FFN phase (tiled, overlaps q/k/v)
  char*  WT  = R + 67633152;
  short* TQ  = (short*)(WT + 0);
  short* TK  = (short*)(WT + 524288);
  short* TVq = (short*)(WT + 1048576);
  short* TU  = (short*)(WT + 1572864);
  short* TVd = (short*)(WT + 3670016);

  prep_weights<<<dim3(1024, 4, 5), 256, 0, stream>>>(Wq, Wk, Wv, WU, WV, TQ, TK, TVq, TU, TVd);
  embed_kernel<<<NROWS / 4, 256, 0, stream>>>(x, ge, invf, h);

  for (int l = 0; l < 4; ++l) {
    ln_tiled<<<NROWS / 32, 256, 0, stream>>>(h, ln1g + l * 256, ln1b + l * 256, hn);
    gemm_t<256, 0><<<dim3(256, 2, 3), 256, 0, stream>>>(
        hn, TQ + l * 65536, TK + l * 65536, TVq + l * 65536,
        bq + l * 256, bk + l * 256, bv + l * 256,
        qb, kb, vb, nullptr, 256);
    attn_chunk_kv<<<1024, 256, 0, stream>>>(kb, vb, St, Zc);
    attn_prefix<<<128, 1024, 0, stream>>>(St, Zc);
    attn_intra<<<1024, 256, 0, stream>>>(qb, kb, vb, St, Zc, h);
    ln_tiled<<<NROWS / 32, 256, 0, stream>>>(h, ln2g + l * 256, ln2b + l * 256, hn);
    gemm_t<256, 1><<<dim3(256, 8, 1), 256, 0, stream>>>(
        hn, TU + l * 262144, nullptr, nullptr,
        bU + l * 1024, nullptr, nullptr,
        mid, nullptr, nullptr, nullptr, 1024);
    gemm_t<1024, 2><<<dim3(256, 2, 1), 256, 0, stream>>>(
        mid, TVd + l * 262144, nullptr, nullptr,
        bV + l * 256, nullptr, nullptr,
        nullptr, nullptr, nullptr, h, 256);
  }
  out_proj<<<NROWS / 4, 256, 0, stream>>>(h, Wout, bout, out);
}